// Round 1
// baseline (4168.132 us; speedup 1.0000x reference)
//
#include <hip/hip_runtime.h>
#include <hip/hip_bf16.h>
#include <math.h>

// ---------------------------------------------------------------------------
// Graph prep kernels
// ---------------------------------------------------------------------------

__global__ void count_deg_k(const int* __restrict__ ei, int E,
                            int* __restrict__ indeg, int* __restrict__ outdeg)
{
    int e = blockIdx.x * blockDim.x + threadIdx.x;
    if (e >= E) return;
    int s = ei[e];
    int d = ei[E + e];
    atomicAdd(&indeg[d], 1);
    atomicAdd(&outdeg[s], 1);
}

// blockIdx.x==0 scans (cnt0->off0), ==1 scans (cnt1->off1). Exclusive scan,
// off[n] = total.
__launch_bounds__(1024)
__global__ void scan_excl2_k(const int* __restrict__ cnt0, int* __restrict__ off0,
                             const int* __restrict__ cnt1, int* __restrict__ off1,
                             int n)
{
    const int* cnt = blockIdx.x ? cnt1 : cnt0;
    int* off = blockIdx.x ? off1 : off0;
    __shared__ int buf[1024];
    __shared__ int carry_s;
    int tid = threadIdx.x;
    if (tid == 0) carry_s = 0;
    __syncthreads();
    for (int base = 0; base < n; base += 1024) {
        int i = base + tid;
        int v = (i < n) ? cnt[i] : 0;
        buf[tid] = v;
        __syncthreads();
        for (int o = 1; o < 1024; o <<= 1) {
            int t = (tid >= o) ? buf[tid - o] : 0;
            __syncthreads();
            if (tid >= o) buf[tid] += t;
            __syncthreads();
        }
        int carry = carry_s;
        if (i < n) off[i] = carry + buf[tid] - v;
        __syncthreads();
        if (tid == 1023) carry_s += buf[1023];
        __syncthreads();
    }
    if (tid == 0) off[n] = carry_s;
}

__global__ void node_prep_k(int n, const int* __restrict__ indeg,
                            const int* __restrict__ in_off, const int* __restrict__ out_off,
                            float* __restrict__ dis, float* __restrict__ selfw,
                            int* __restrict__ cur_in, int* __restrict__ cur_out)
{
    int i = blockIdx.x * blockDim.x + threadIdx.x;
    if (i >= n) return;
    float dg = (float)indeg[i] + 1.0f;
    dis[i] = rsqrtf(dg);
    selfw[i] = 1.0f / dg;
    cur_in[i] = in_off[i];
    cur_out[i] = out_off[i];
}

__global__ void fill_csr_k(const int* __restrict__ ei, int E,
                           int* __restrict__ cur_in, int* __restrict__ cur_out,
                           int* __restrict__ csr_in, int* __restrict__ csr_out)
{
    int e = blockIdx.x * blockDim.x + threadIdx.x;
    if (e >= E) return;
    int s = ei[e];
    int d = ei[E + e];
    int p = atomicAdd(&cur_in[d], 1);
    csr_in[p] = s;
    int q = atomicAdd(&cur_out[s], 1);
    csr_out[q] = d;
}

// ---------------------------------------------------------------------------
// Fused projector: h = relu(LN(X@W1 + b1))@W2 + b2, optional sigmoid mix with
// `last`. X:[N,1024], W1:[1024,128], W2:[128,128], out:[N,128].
// Block = 256 threads, tile = 64 rows x 128 cols (full width).
// ---------------------------------------------------------------------------
__launch_bounds__(256)
__global__ void proj_fused_k(const float* __restrict__ X,
                             const float* __restrict__ W1,
                             const float* __restrict__ b1,
                             const float* __restrict__ lng,
                             const float* __restrict__ lnb,
                             const float* __restrict__ W2,
                             const float* __restrict__ b2,
                             const float* __restrict__ alphas, int layer,
                             const float* __restrict__ last,
                             float* __restrict__ out, int nrows)
{
    __shared__ float Xs[64][36];   // 64 rows x 32 k (pad->36 for f4 align)
    __shared__ float Ws[32][132];  // 32 k x 128 cols
    __shared__ float Hs[64][132];  // LN(relu) result, 64 x 128

    const int tid = threadIdx.x;
    const int tx = tid & 31;       // col group: cols tx*4 .. tx*4+3
    const int ty = tid >> 5;       // row group: rows ty + 8*r
    const int row0 = blockIdx.x * 64;

    float acc[8][4];
#pragma unroll
    for (int r = 0; r < 8; ++r) { acc[r][0]=0.f; acc[r][1]=0.f; acc[r][2]=0.f; acc[r][3]=0.f; }

    for (int k0 = 0; k0 < 1024; k0 += 32) {
#pragma unroll
        for (int it = 0; it < 2; ++it) {
            int r = (tid >> 3) + it * 32;
            int c = (tid & 7) * 4;
            float4 v = make_float4(0.f, 0.f, 0.f, 0.f);
            int gr = row0 + r;
            if (gr < nrows) v = *(const float4*)&X[(size_t)gr * 1024 + k0 + c];
            *(float4*)&Xs[r][c] = v;
        }
#pragma unroll
        for (int it = 0; it < 4; ++it) {
            int r = (tid >> 5) + it * 8;
            int c = (tid & 31) * 4;
            *(float4*)&Ws[r][c] = *(const float4*)&W1[(size_t)(k0 + r) * 128 + c];
        }
        __syncthreads();
#pragma unroll
        for (int kk = 0; kk < 32; ++kk) {
            float4 b4 = *(const float4*)&Ws[kk][tx * 4];
#pragma unroll
            for (int r = 0; r < 8; ++r) {
                float a = Xs[ty + 8 * r][kk];
                acc[r][0] = fmaf(a, b4.x, acc[r][0]);
                acc[r][1] = fmaf(a, b4.y, acc[r][1]);
                acc[r][2] = fmaf(a, b4.z, acc[r][2]);
                acc[r][3] = fmaf(a, b4.w, acc[r][3]);
            }
        }
        __syncthreads();
    }

    // bias + LayerNorm + ReLU -> Hs
    {
        float4 bv = *(const float4*)&b1[tx * 4];
        float4 gv = *(const float4*)&lng[tx * 4];
        float4 nv = *(const float4*)&lnb[tx * 4];
#pragma unroll
        for (int r = 0; r < 8; ++r) {
            acc[r][0] += bv.x; acc[r][1] += bv.y; acc[r][2] += bv.z; acc[r][3] += bv.w;
            float s = acc[r][0] + acc[r][1] + acc[r][2] + acc[r][3];
            float q = acc[r][0]*acc[r][0] + acc[r][1]*acc[r][1]
                    + acc[r][2]*acc[r][2] + acc[r][3]*acc[r][3];
#pragma unroll
            for (int m = 1; m < 32; m <<= 1) {
                s += __shfl_xor(s, m);
                q += __shfl_xor(q, m);
            }
            float mean = s * (1.0f / 128.0f);
            float var  = q * (1.0f / 128.0f) - mean * mean;
            float inv  = rsqrtf(var + 1e-5f);
            float4 h;
            h.x = fmaxf((acc[r][0] - mean) * inv * gv.x + nv.x, 0.f);
            h.y = fmaxf((acc[r][1] - mean) * inv * gv.y + nv.y, 0.f);
            h.z = fmaxf((acc[r][2] - mean) * inv * gv.z + nv.z, 0.f);
            h.w = fmaxf((acc[r][3] - mean) * inv * gv.w + nv.w, 0.f);
            *(float4*)&Hs[ty + 8 * r][tx * 4] = h;
        }
    }
    __syncthreads();

    // GEMM2: Hs[64,128] @ W2[128,128]
    float acc2[8][4];
#pragma unroll
    for (int r = 0; r < 8; ++r) { acc2[r][0]=0.f; acc2[r][1]=0.f; acc2[r][2]=0.f; acc2[r][3]=0.f; }
    for (int k0 = 0; k0 < 128; k0 += 32) {
#pragma unroll
        for (int it = 0; it < 4; ++it) {
            int r = (tid >> 5) + it * 8;
            int c = (tid & 31) * 4;
            *(float4*)&Ws[r][c] = *(const float4*)&W2[(size_t)(k0 + r) * 128 + c];
        }
        __syncthreads();
#pragma unroll
        for (int kk = 0; kk < 32; ++kk) {
            float4 b4 = *(const float4*)&Ws[kk][tx * 4];
#pragma unroll
            for (int r = 0; r < 8; ++r) {
                float a = Hs[ty + 8 * r][k0 + kk];
                acc2[r][0] = fmaf(a, b4.x, acc2[r][0]);
                acc2[r][1] = fmaf(a, b4.y, acc2[r][1]);
                acc2[r][2] = fmaf(a, b4.z, acc2[r][2]);
                acc2[r][3] = fmaf(a, b4.w, acc2[r][3]);
            }
        }
        __syncthreads();
    }

    float4 b2v = *(const float4*)&b2[tx * 4];
    float asig = 0.f, omas = 0.f;
    if (last) {
        float al = alphas[layer];
        asig = 1.0f / (1.0f + expf(-al * 10.0f));   // T = 0.1
        omas = 1.0f - asig;
    }
#pragma unroll
    for (int r = 0; r < 8; ++r) {
        int gr = row0 + ty + 8 * r;
        if (gr >= nrows) continue;
        float4 o;
        o.x = acc2[r][0] + b2v.x;
        o.y = acc2[r][1] + b2v.y;
        o.z = acc2[r][2] + b2v.z;
        o.w = acc2[r][3] + b2v.w;
        if (last) {
            float4 lv = *(const float4*)&last[(size_t)gr * 128 + tx * 4];
            o.x = asig * o.x + omas * lv.x;
            o.y = asig * o.y + omas * lv.y;
            o.z = asig * o.z + omas * lv.z;
            o.w = asig * o.w + omas * lv.w;
        }
        *(float4*)&out[(size_t)gr * 128 + tx * 4] = o;
    }
}

// ---------------------------------------------------------------------------
// AGG: y[n] = dis[n] * sum_{s in in(n)} dis[s]*x[s]  +  selfw[n]*x[n]  (+bias)
// x,y: [N,128]. One wave (64 lanes) per node, 2 floats per lane.
// ---------------------------------------------------------------------------
__launch_bounds__(256)
__global__ void agg_k(const float* __restrict__ x, float* __restrict__ y,
                      const int* __restrict__ off, const int* __restrict__ csr,
                      const float* __restrict__ dis, const float* __restrict__ selfw,
                      const float* __restrict__ bias, int N)
{
    int node = blockIdx.x * 4 + (threadIdx.x >> 6);
    if (node >= N) return;
    int lane = threadIdx.x & 63;
    int beg = off[node], end = off[node + 1];
    float2 acc = make_float2(0.f, 0.f);
    for (int e = beg; e < end; ++e) {
        int s = csr[e];
        float w = dis[s];
        float2 xv = *(const float2*)&x[(size_t)s * 128 + lane * 2];
        acc.x = fmaf(w, xv.x, acc.x);
        acc.y = fmaf(w, xv.y, acc.y);
    }
    float dn = dis[node], sw = selfw[node];
    float2 xo = *(const float2*)&x[(size_t)node * 128 + lane * 2];
    float2 r;
    r.x = dn * acc.x + sw * xo.x;
    r.y = dn * acc.y + sw * xo.y;
    if (bias) { r.x += bias[lane * 2]; r.y += bias[lane * 2 + 1]; }
    *(float2*)&y[(size_t)node * 128 + lane * 2] = r;
}

// ---------------------------------------------------------------------------
// Generic small GEMM: C[M,OUT] = A[M,Kd] @ B[Kd,OUT] (+bias) (relu optional)
// 64x64 tile, 256 threads, 4x4 acc per thread.
// ---------------------------------------------------------------------------
template <bool RELU>
__launch_bounds__(256)
__global__ void gemm_bias_k(const float* __restrict__ A, const float* __restrict__ Bm,
                            const float* __restrict__ bias, float* __restrict__ Cm,
                            int M, int Kd, int OUT)
{
    __shared__ float As[64][36];
    __shared__ float Bs[32][68];
    const int tid = threadIdx.x;
    const int tx = tid & 15;
    const int ty = tid >> 4;
    const int m0 = blockIdx.x * 64;
    const int n0 = blockIdx.y * 64;

    float acc[4][4];
#pragma unroll
    for (int r = 0; r < 4; ++r) { acc[r][0]=0.f; acc[r][1]=0.f; acc[r][2]=0.f; acc[r][3]=0.f; }

    for (int k0 = 0; k0 < Kd; k0 += 32) {
#pragma unroll
        for (int it = 0; it < 2; ++it) {
            int r = (tid >> 3) + it * 32;
            int c = (tid & 7) * 4;
            float4 v = make_float4(0.f, 0.f, 0.f, 0.f);
            int gr = m0 + r;
            if (gr < M) v = *(const float4*)&A[(size_t)gr * Kd + k0 + c];
            *(float4*)&As[r][c] = v;
        }
#pragma unroll
        for (int it = 0; it < 2; ++it) {
            int r = (tid >> 4) + it * 16;
            int c = (tid & 15) * 4;
            *(float4*)&Bs[r][c] = *(const float4*)&Bm[(size_t)(k0 + r) * OUT + n0 + c];
        }
        __syncthreads();
#pragma unroll
        for (int kk = 0; kk < 32; ++kk) {
            float4 b4 = *(const float4*)&Bs[kk][tx * 4];
#pragma unroll
            for (int r = 0; r < 4; ++r) {
                float a = As[ty + 16 * r][kk];
                acc[r][0] = fmaf(a, b4.x, acc[r][0]);
                acc[r][1] = fmaf(a, b4.y, acc[r][1]);
                acc[r][2] = fmaf(a, b4.z, acc[r][2]);
                acc[r][3] = fmaf(a, b4.w, acc[r][3]);
            }
        }
        __syncthreads();
    }

    float4 bb = make_float4(0.f, 0.f, 0.f, 0.f);
    if (bias) bb = *(const float4*)&bias[n0 + tx * 4];
#pragma unroll
    for (int r = 0; r < 4; ++r) {
        int gr = m0 + ty + 16 * r;
        if (gr >= M) continue;
        float4 o;
        o.x = acc[r][0] + bb.x;
        o.y = acc[r][1] + bb.y;
        o.z = acc[r][2] + bb.z;
        o.w = acc[r][3] + bb.w;
        if (RELU) {
            o.x = fmaxf(o.x, 0.f); o.y = fmaxf(o.y, 0.f);
            o.z = fmaxf(o.z, 0.f); o.w = fmaxf(o.w, 0.f);
        }
        *(float4*)&Cm[(size_t)gr * OUT + n0 + tx * 4] = o;
    }
}

// ---------------------------------------------------------------------------
// Pooling (only at mapped nodes) + classifier.
// Block of 128 threads per batch element.
// ---------------------------------------------------------------------------
__launch_bounds__(128)
__global__ void pool_clf_k(const float* __restrict__ last, const int* __restrict__ mapping,
                           const int* __restrict__ in_off, const int* __restrict__ csr_in,
                           const int* __restrict__ out_off, const int* __restrict__ csr_out,
                           const int* __restrict__ indeg, const int* __restrict__ outdeg,
                           const float* __restrict__ clfW, const float* __restrict__ clfb,
                           float* __restrict__ out, int C)
{
    int b = blockIdx.x;
    int tid = threadIdx.x;   // 0..127 = feature dim
    int n = mapping[b];

    float s = 0.f;
    int ob = out_off[n], oe = out_off[n + 1];
    for (int e = ob; e < oe; ++e) s += last[(size_t)csr_out[e] * 128 + tid];
    int ib = in_off[n], ie = in_off[n + 1];
    for (int e = ib; e < ie; ++e) s += last[(size_t)csr_in[e] * 128 + tid];

    float lv = last[(size_t)n * 128 + tid];
    float cnt = (float)(indeg[n] + outdeg[n]);
    float pooled = (lv + s) / (1.0f + cnt);

    __shared__ float feat[256];
    feat[tid] = lv;
    feat[128 + tid] = pooled;
    __syncthreads();

    for (int c = tid; c < C; c += blockDim.x) {
        float o = clfb[c];
        for (int j = 0; j < 256; ++j) o = fmaf(feat[j], clfW[j * C + c], o);
        out[(size_t)b * C + c] = o;
    }
}

// ---------------------------------------------------------------------------
// Host launcher
// ---------------------------------------------------------------------------
extern "C" void kernel_launch(void* const* d_in, const int* in_sizes, int n_in,
                              void* d_out, int out_size, void* d_ws, size_t ws_size,
                              hipStream_t stream)
{
    const float* hidden = (const float*)d_in[0];
    const float* pW1    = (const float*)d_in[1];
    const float* pb1    = (const float*)d_in[2];
    const float* lng    = (const float*)d_in[3];
    const float* lnb    = (const float*)d_in[4];
    const float* pW2    = (const float*)d_in[5];
    const float* pb2    = (const float*)d_in[6];
    const float* alphas = (const float*)d_in[7];
    const float* gW1    = (const float*)d_in[8];
    const float* gb1    = (const float*)d_in[9];
    const float* gW2    = (const float*)d_in[10];
    const float* gb2    = (const float*)d_in[11];
    const float* clfW   = (const float*)d_in[12];
    const float* clfb   = (const float*)d_in[13];
    const int*   ei     = (const int*)d_in[14];
    const int*   mapping= (const int*)d_in[15];

    const int L   = in_sizes[7];                 // 2
    const int K   = in_sizes[2] / L;             // 128
    const int H   = in_sizes[9] / L;             // 256
    const int C   = in_sizes[13];                // 40
    const int DLM = in_sizes[1] / (L * K);       // 1024
    const int N   = in_sizes[0] / (L * DLM);     // 100000
    const int E   = in_sizes[14] / 2;            // 3200000
    const int B   = in_sizes[15];                // 1024

    // workspace carve (all 256B aligned)
    char* ws = (char*)d_ws;
    size_t off = 0;
    auto carve = [&](size_t bytes) -> char* {
        char* p = ws + off;
        off += (bytes + 255) & ~(size_t)255;
        return p;
    };
    int*   indeg   = (int*)carve((size_t)N * 4);
    int*   outdeg  = (int*)carve((size_t)N * 4);
    int*   in_off  = (int*)carve((size_t)(N + 1) * 4);
    int*   out_off = (int*)carve((size_t)(N + 1) * 4);
    int*   cur_in  = (int*)carve((size_t)N * 4);
    int*   cur_out = (int*)carve((size_t)N * 4);
    float* dis     = (float*)carve((size_t)N * 4);
    float* selfw   = (float*)carve((size_t)N * 4);
    int*   csr_in  = (int*)carve((size_t)E * 4);
    int*   csr_out = (int*)carve((size_t)E * 4);
    float* bufA    = (float*)carve((size_t)N * K * 4);   // h2 / v
    float* bufB    = (float*)carve((size_t)N * K * 4);   // u / last
    float* bufC    = (float*)carve((size_t)N * H * 4);   // z
    (void)ws_size; (void)n_in; (void)out_size;

    // 1) degrees
    hipMemsetAsync(indeg, 0, (size_t)N * 4, stream);
    hipMemsetAsync(outdeg, 0, (size_t)N * 4, stream);
    count_deg_k<<<dim3((E + 255) / 256), 256, 0, stream>>>(ei, E, indeg, outdeg);

    // 2) CSR offsets
    scan_excl2_k<<<dim3(2), 1024, 0, stream>>>(indeg, in_off, outdeg, out_off, N);

    // 3) node constants + cursors
    node_prep_k<<<dim3((N + 255) / 256), 256, 0, stream>>>(N, indeg, in_off, out_off,
                                                           dis, selfw, cur_in, cur_out);

    // 4) CSR fill
    fill_csr_k<<<dim3((E + 255) / 256), 256, 0, stream>>>(ei, E, cur_in, cur_out,
                                                          csr_in, csr_out);

    // 5) layers
    for (int i = 0; i < L; ++i) {
        proj_fused_k<<<dim3((N + 63) / 64), 256, 0, stream>>>(
            hidden + (size_t)i * N * DLM,
            pW1 + (size_t)i * DLM * K,
            pb1 + (size_t)i * K,
            lng + (size_t)i * K,
            lnb + (size_t)i * K,
            pW2 + (size_t)i * K * K,
            pb2 + (size_t)i * K,
            alphas, i,
            (i > 0) ? bufB : nullptr,
            bufA, N);

        // u = A_hat @ h2
        agg_k<<<dim3((N + 3) / 4), 256, 0, stream>>>(bufA, bufB, in_off, csr_in,
                                                     dis, selfw, nullptr, N);
        // z = relu(u @ gcn_W1 + gcn_b1)
        gemm_bias_k<true><<<dim3((N + 63) / 64, H / 64), 256, 0, stream>>>(
            bufB, gW1 + (size_t)i * K * H, gb1 + (size_t)i * H, bufC, N, K, H);
        // v = z @ gcn_W2
        gemm_bias_k<false><<<dim3((N + 63) / 64, K / 64), 256, 0, stream>>>(
            bufC, gW2 + (size_t)i * H * K, nullptr, bufA, N, H, K);
        // last = A_hat @ v + gcn_b2
        agg_k<<<dim3((N + 3) / 4), 256, 0, stream>>>(bufA, bufB, in_off, csr_in,
                                                     dis, selfw, gb2 + (size_t)i * K, N);
    }

    // 6) pooling + classifier
    pool_clf_k<<<dim3(B), 128, 0, stream>>>(bufB, mapping, in_off, csr_in,
                                            out_off, csr_out, indeg, outdeg,
                                            clfW, clfb, (float*)d_out, C);
}

// Round 2
// 2961.065 us; speedup vs baseline: 1.4076x; 1.4076x over previous
//
#include <hip/hip_runtime.h>
#include <hip/hip_bf16.h>
#include <math.h>

using short8 = __attribute__((ext_vector_type(8))) short;
using f32x4  = __attribute__((ext_vector_type(4))) float;

__device__ __forceinline__ short f2bf(float f) {
    unsigned u = __float_as_uint(f);
    u = (u + 0x7FFFu + ((u >> 16) & 1u)) >> 16;
    return (short)u;
}

// ---------------------------------------------------------------------------
// Graph prep kernels
// ---------------------------------------------------------------------------

__global__ void count_deg_k(const int* __restrict__ ei, int E,
                            int* __restrict__ indeg, int* __restrict__ outdeg)
{
    int e = blockIdx.x * blockDim.x + threadIdx.x;
    if (e >= E) return;
    int s = ei[e];
    int d = ei[E + e];
    atomicAdd(&indeg[d], 1);
    atomicAdd(&outdeg[s], 1);
}

__launch_bounds__(1024)
__global__ void scan_excl2_k(const int* __restrict__ cnt0, int* __restrict__ off0,
                             const int* __restrict__ cnt1, int* __restrict__ off1,
                             int n)
{
    const int* cnt = blockIdx.x ? cnt1 : cnt0;
    int* off = blockIdx.x ? off1 : off0;
    __shared__ int buf[1024];
    __shared__ int carry_s;
    int tid = threadIdx.x;
    if (tid == 0) carry_s = 0;
    __syncthreads();
    for (int base = 0; base < n; base += 1024) {
        int i = base + tid;
        int v = (i < n) ? cnt[i] : 0;
        buf[tid] = v;
        __syncthreads();
        for (int o = 1; o < 1024; o <<= 1) {
            int t = (tid >= o) ? buf[tid - o] : 0;
            __syncthreads();
            if (tid >= o) buf[tid] += t;
            __syncthreads();
        }
        int carry = carry_s;
        if (i < n) off[i] = carry + buf[tid] - v;
        __syncthreads();
        if (tid == 1023) carry_s += buf[1023];
        __syncthreads();
    }
    if (tid == 0) off[n] = carry_s;
}

__global__ void node_prep_k(int n, const int* __restrict__ indeg,
                            const int* __restrict__ in_off, const int* __restrict__ out_off,
                            float* __restrict__ dis, float* __restrict__ selfw,
                            int* __restrict__ cur_in, int* __restrict__ cur_out)
{
    int i = blockIdx.x * blockDim.x + threadIdx.x;
    if (i >= n) return;
    float dg = (float)indeg[i] + 1.0f;
    dis[i] = rsqrtf(dg);
    selfw[i] = 1.0f / dg;
    cur_in[i] = in_off[i];
    cur_out[i] = out_off[i];
}

__global__ void fill_csr_k(const int* __restrict__ ei, int E,
                           int* __restrict__ cur_in, int* __restrict__ cur_out,
                           int* __restrict__ csr_in, int* __restrict__ csr_out)
{
    int e = blockIdx.x * blockDim.x + threadIdx.x;
    if (e >= E) return;
    int s = ei[e];
    int d = ei[E + e];
    int p = atomicAdd(&cur_in[d], 1);
    csr_in[p] = s;
    int q = atomicAdd(&cur_out[s], 1);
    csr_out[q] = d;
}

// Transpose + fp32->bf16: src [R][Cc] fp32 -> dst [Cc][R] bf16
__global__ void transpose_w_k(const float* __restrict__ src, short* __restrict__ dst,
                              int R, int Cc)
{
    int idx = blockIdx.x * blockDim.x + threadIdx.x;
    if (idx >= R * Cc) return;
    int r = idx / Cc;
    int c = idx - r * Cc;
    dst[(size_t)c * R + r] = f2bf(src[idx]);
}

// ---------------------------------------------------------------------------
// Fused projector (MFMA): h = relu(LN(X@W1 + b1))@W2 + b2, optional sigmoid
// mix with `last`. X:[N,1024] fp32, W1t:[128][1024] bf16 (pre-transposed),
// W2t:[128][128] bf16, out:[N,128] fp32.
// Block = 256 threads (4 waves), tile = 64 rows x 128 cols.
// Wave w owns rows w*16..w*16+15; 8 col-frags of 16x16x32 bf16 MFMA.
// LDS carve (shorts):
//   Xs  [64][72]  at 0        (4608)   } GEMM1 phase
//   W1t [128][72] at 4608     (9216)   }
//   W2t [128][136] at 0       (17408)  } GEMM2 phase (reuses Xs+W1t)
//   Hs  [64][136] at 17408    (8704)
// total 26112 shorts = 52224 B -> 3 blocks/CU
// ---------------------------------------------------------------------------
__launch_bounds__(256)
__global__ void proj_fused_k(const float* __restrict__ X,
                             const short* __restrict__ W1t,
                             const float* __restrict__ b1,
                             const float* __restrict__ lng,
                             const float* __restrict__ lnb,
                             const short* __restrict__ W2t,
                             const float* __restrict__ b2,
                             const float* __restrict__ alphas, int layer,
                             const float* __restrict__ last,
                             float* __restrict__ out, int nrows)
{
    __shared__ short S[26112];

    const int tid  = threadIdx.x;
    const int lane = tid & 63;
    const int wave = tid >> 6;
    const int g    = lane >> 4;     // k-group / row-group
    const int lr   = lane & 15;     // A-row / B-col / D-col
    const int wrow = wave * 16;
    const int row0 = blockIdx.x * 64;

    f32x4 acc[8];
#pragma unroll
    for (int f = 0; f < 8; ++f) acc[f] = (f32x4){0.f, 0.f, 0.f, 0.f};

    // ---------------- GEMM1: X[64,1024] @ W1[1024,128] -------------------
    for (int k0 = 0; k0 < 1024; k0 += 64) {
        // stage X tile -> bf16 LDS  (64 rows x 64 k)
        {
            int r  = tid >> 2;
            int c0 = (tid & 3) * 16;
            int gr = row0 + r;
            float4 v0 = make_float4(0.f,0.f,0.f,0.f), v1 = v0, v2 = v0, v3 = v0;
            if (gr < nrows) {
                const float* xp = X + (size_t)gr * 1024 + k0 + c0;
                v0 = *(const float4*)&xp[0];
                v1 = *(const float4*)&xp[4];
                v2 = *(const float4*)&xp[8];
                v3 = *(const float4*)&xp[12];
            }
            short8 p0, p1;
            p0[0]=f2bf(v0.x); p0[1]=f2bf(v0.y); p0[2]=f2bf(v0.z); p0[3]=f2bf(v0.w);
            p0[4]=f2bf(v1.x); p0[5]=f2bf(v1.y); p0[6]=f2bf(v1.z); p0[7]=f2bf(v1.w);
            p1[0]=f2bf(v2.x); p1[1]=f2bf(v2.y); p1[2]=f2bf(v2.z); p1[3]=f2bf(v2.w);
            p1[4]=f2bf(v3.x); p1[5]=f2bf(v3.y); p1[6]=f2bf(v3.z); p1[7]=f2bf(v3.w);
            *(short8*)&S[r * 72 + c0]     = p0;
            *(short8*)&S[r * 72 + c0 + 8] = p1;
        }
        // stage W1t tile (128 cols x 64 k), already bf16 + transposed
        {
            int c  = tid >> 1;
            int kb = (tid & 1) * 32;
            const short* wp = W1t + (size_t)c * 1024 + k0 + kb;
            short* dp = &S[4608 + c * 72 + kb];
#pragma unroll
            for (int m = 0; m < 4; ++m)
                *(short8*)&dp[m * 8] = *(const short8*)&wp[m * 8];
        }
        __syncthreads();
#pragma unroll
        for (int kk = 0; kk < 64; kk += 32) {
            short8 a = *(short8*)&S[(wrow + lr) * 72 + kk + g * 8];
#pragma unroll
            for (int f = 0; f < 8; ++f) {
                short8 b = *(short8*)&S[4608 + (f * 16 + lr) * 72 + kk + g * 8];
                acc[f] = __builtin_amdgcn_mfma_f32_16x16x32_bf16(a, b, acc[f], 0, 0, 0);
            }
        }
        __syncthreads();
    }

    // ---------------- bias + LayerNorm + ReLU -> Hs (bf16) ---------------
    {
        float b1v[8], gv[8], bv[8];
#pragma unroll
        for (int f = 0; f < 8; ++f) {
            int col = f * 16 + lr;
            b1v[f] = b1[col]; gv[f] = lng[col]; bv[f] = lnb[col];
        }
#pragma unroll
        for (int j = 0; j < 4; ++j) {
            float hv[8];
            float s = 0.f, q = 0.f;
#pragma unroll
            for (int f = 0; f < 8; ++f) {
                float t = acc[f][j] + b1v[f];
                hv[f] = t;
                s += t; q += t * t;
            }
#pragma unroll
            for (int m = 1; m < 16; m <<= 1) {
                s += __shfl_xor(s, m);
                q += __shfl_xor(q, m);
            }
            float mean = s * (1.0f / 128.0f);
            float var  = q * (1.0f / 128.0f) - mean * mean;
            float inv  = rsqrtf(var + 1e-5f);
            int rloc = wrow + 4 * g + j;
#pragma unroll
            for (int f = 0; f < 8; ++f) {
                float h = fmaxf((hv[f] - mean) * inv * gv[f] + bv[f], 0.f);
                S[17408 + rloc * 136 + f * 16 + lr] = f2bf(h);
            }
        }
    }
    // stage W2t (128x128 bf16) into LDS (reuses GEMM1 region)
    {
        int c  = tid >> 1;
        int kb = (tid & 1) * 64;
        const short* wp = W2t + (size_t)c * 128 + kb;
        short* dp = &S[c * 136 + kb];
#pragma unroll
        for (int m = 0; m < 8; ++m)
            *(short8*)&dp[m * 8] = *(const short8*)&wp[m * 8];
    }
    __syncthreads();

    // ---------------- GEMM2: Hs[64,128] @ W2[128,128] --------------------
    f32x4 acc2[8];
#pragma unroll
    for (int f = 0; f < 8; ++f) acc2[f] = (f32x4){0.f, 0.f, 0.f, 0.f};
#pragma unroll
    for (int kk = 0; kk < 128; kk += 32) {
        short8 a = *(short8*)&S[17408 + (wrow + lr) * 136 + kk + g * 8];
#pragma unroll
        for (int f = 0; f < 8; ++f) {
            short8 b = *(short8*)&S[(f * 16 + lr) * 136 + kk + g * 8];
            acc2[f] = __builtin_amdgcn_mfma_f32_16x16x32_bf16(a, b, acc2[f], 0, 0, 0);
        }
    }

    // ---------------- epilogue: +b2, sigmoid-mix, store ------------------
    float b2v[8];
#pragma unroll
    for (int f = 0; f < 8; ++f) b2v[f] = b2[f * 16 + lr];
    float asig = 0.f, omas = 0.f;
    if (last) {
        float al = alphas[layer];
        asig = 1.0f / (1.0f + expf(-al * 10.0f));   // T = 0.1
        omas = 1.0f - asig;
    }
#pragma unroll
    for (int j = 0; j < 4; ++j) {
        int gr = row0 + wrow + 4 * g + j;
        if (gr >= nrows) continue;
#pragma unroll
        for (int f = 0; f < 8; ++f) {
            int col = f * 16 + lr;
            float o = acc2[f][j] + b2v[f];
            if (last) o = asig * o + omas * last[(size_t)gr * 128 + col];
            out[(size_t)gr * 128 + col] = o;
        }
    }
}

// ---------------------------------------------------------------------------
// AGG: y[n] = dis[n] * sum_{s in in(n)} dis[s]*x[s]  +  selfw[n]*x[n]  (+bias)
// ---------------------------------------------------------------------------
__launch_bounds__(256)
__global__ void agg_k(const float* __restrict__ x, float* __restrict__ y,
                      const int* __restrict__ off, const int* __restrict__ csr,
                      const float* __restrict__ dis, const float* __restrict__ selfw,
                      const float* __restrict__ bias, int N)
{
    int node = blockIdx.x * 4 + (threadIdx.x >> 6);
    if (node >= N) return;
    int lane = threadIdx.x & 63;
    int beg = off[node], end = off[node + 1];
    float2 acc = make_float2(0.f, 0.f);
    for (int e = beg; e < end; ++e) {
        int s = csr[e];
        float w = dis[s];
        float2 xv = *(const float2*)&x[(size_t)s * 128 + lane * 2];
        acc.x = fmaf(w, xv.x, acc.x);
        acc.y = fmaf(w, xv.y, acc.y);
    }
    float dn = dis[node], sw = selfw[node];
    float2 xo = *(const float2*)&x[(size_t)node * 128 + lane * 2];
    float2 r;
    r.x = dn * acc.x + sw * xo.x;
    r.y = dn * acc.y + sw * xo.y;
    if (bias) { r.x += bias[lane * 2]; r.y += bias[lane * 2 + 1]; }
    *(float2*)&y[(size_t)node * 128 + lane * 2] = r;
}

// ---------------------------------------------------------------------------
// Generic small GEMM: C[M,OUT] = A[M,Kd] @ B[Kd,OUT] (+bias) (relu optional)
// ---------------------------------------------------------------------------
template <bool RELU>
__launch_bounds__(256)
__global__ void gemm_bias_k(const float* __restrict__ A, const float* __restrict__ Bm,
                            const float* __restrict__ bias, float* __restrict__ Cm,
                            int M, int Kd, int OUT)
{
    __shared__ float As[64][36];
    __shared__ float Bs[32][68];
    const int tid = threadIdx.x;
    const int tx = tid & 15;
    const int ty = tid >> 4;
    const int m0 = blockIdx.x * 64;
    const int n0 = blockIdx.y * 64;

    float acc[4][4];
#pragma unroll
    for (int r = 0; r < 4; ++r) { acc[r][0]=0.f; acc[r][1]=0.f; acc[r][2]=0.f; acc[r][3]=0.f; }

    for (int k0 = 0; k0 < Kd; k0 += 32) {
#pragma unroll
        for (int it = 0; it < 2; ++it) {
            int r = (tid >> 3) + it * 32;
            int c = (tid & 7) * 4;
            float4 v = make_float4(0.f, 0.f, 0.f, 0.f);
            int gr = m0 + r;
            if (gr < M) v = *(const float4*)&A[(size_t)gr * Kd + k0 + c];
            *(float4*)&As[r][c] = v;
        }
#pragma unroll
        for (int it = 0; it < 2; ++it) {
            int r = (tid >> 4) + it * 16;
            int c = (tid & 15) * 4;
            *(float4*)&Bs[r][c] = *(const float4*)&Bm[(size_t)(k0 + r) * OUT + n0 + c];
        }
        __syncthreads();
#pragma unroll
        for (int kk = 0; kk < 32; ++kk) {
            float4 b4 = *(const float4*)&Bs[kk][tx * 4];
#pragma unroll
            for (int r = 0; r < 4; ++r) {
                float a = As[ty + 16 * r][kk];
                acc[r][0] = fmaf(a, b4.x, acc[r][0]);
                acc[r][1] = fmaf(a, b4.y, acc[r][1]);
                acc[r][2] = fmaf(a, b4.z, acc[r][2]);
                acc[r][3] = fmaf(a, b4.w, acc[r][3]);
            }
        }
        __syncthreads();
    }

    float4 bb = make_float4(0.f, 0.f, 0.f, 0.f);
    if (bias) bb = *(const float4*)&bias[n0 + tx * 4];
#pragma unroll
    for (int r = 0; r < 4; ++r) {
        int gr = m0 + ty + 16 * r;
        if (gr >= M) continue;
        float4 o;
        o.x = acc[r][0] + bb.x;
        o.y = acc[r][1] + bb.y;
        o.z = acc[r][2] + bb.z;
        o.w = acc[r][3] + bb.w;
        if (RELU) {
            o.x = fmaxf(o.x, 0.f); o.y = fmaxf(o.y, 0.f);
            o.z = fmaxf(o.z, 0.f); o.w = fmaxf(o.w, 0.f);
        }
        *(float4*)&Cm[(size_t)gr * OUT + n0 + tx * 4] = o;
    }
}

// ---------------------------------------------------------------------------
// Pooling (only at mapped nodes) + classifier.
// ---------------------------------------------------------------------------
__launch_bounds__(128)
__global__ void pool_clf_k(const float* __restrict__ last, const int* __restrict__ mapping,
                           const int* __restrict__ in_off, const int* __restrict__ csr_in,
                           const int* __restrict__ out_off, const int* __restrict__ csr_out,
                           const int* __restrict__ indeg, const int* __restrict__ outdeg,
                           const float* __restrict__ clfW, const float* __restrict__ clfb,
                           float* __restrict__ out, int C)
{
    int b = blockIdx.x;
    int tid = threadIdx.x;   // 0..127 = feature dim
    int n = mapping[b];

    float s = 0.f;
    int ob = out_off[n], oe = out_off[n + 1];
    for (int e = ob; e < oe; ++e) s += last[(size_t)csr_out[e] * 128 + tid];
    int ib = in_off[n], ie = in_off[n + 1];
    for (int e = ib; e < ie; ++e) s += last[(size_t)csr_in[e] * 128 + tid];

    float lv = last[(size_t)n * 128 + tid];
    float cnt = (float)(indeg[n] + outdeg[n]);
    float pooled = (lv + s) / (1.0f + cnt);

    __shared__ float feat[256];
    feat[tid] = lv;
    feat[128 + tid] = pooled;
    __syncthreads();

    for (int c = tid; c < C; c += blockDim.x) {
        float o = clfb[c];
        for (int j = 0; j < 256; ++j) o = fmaf(feat[j], clfW[j * C + c], o);
        out[(size_t)b * C + c] = o;
    }
}

// ---------------------------------------------------------------------------
// Host launcher
// ---------------------------------------------------------------------------
extern "C" void kernel_launch(void* const* d_in, const int* in_sizes, int n_in,
                              void* d_out, int out_size, void* d_ws, size_t ws_size,
                              hipStream_t stream)
{
    const float* hidden = (const float*)d_in[0];
    const float* pW1    = (const float*)d_in[1];
    const float* pb1    = (const float*)d_in[2];
    const float* lng    = (const float*)d_in[3];
    const float* lnb    = (const float*)d_in[4];
    const float* pW2    = (const float*)d_in[5];
    const float* pb2    = (const float*)d_in[6];
    const float* alphas = (const float*)d_in[7];
    const float* gW1    = (const float*)d_in[8];
    const float* gb1    = (const float*)d_in[9];
    const float* gW2    = (const float*)d_in[10];
    const float* gb2    = (const float*)d_in[11];
    const float* clfW   = (const float*)d_in[12];
    const float* clfb   = (const float*)d_in[13];
    const int*   ei     = (const int*)d_in[14];
    const int*   mapping= (const int*)d_in[15];

    const int L   = in_sizes[7];                 // 2
    const int K   = in_sizes[2] / L;             // 128
    const int H   = in_sizes[9] / L;             // 256
    const int C   = in_sizes[13];                // 40
    const int DLM = in_sizes[1] / (L * K);       // 1024
    const int N   = in_sizes[0] / (L * DLM);     // 100000
    const int E   = in_sizes[14] / 2;            // 3200000
    const int B   = in_sizes[15];                // 1024

    char* ws = (char*)d_ws;
    size_t off = 0;
    auto carve = [&](size_t bytes) -> char* {
        char* p = ws + off;
        off += (bytes + 255) & ~(size_t)255;
        return p;
    };
    int*   indeg   = (int*)carve((size_t)N * 4);
    int*   outdeg  = (int*)carve((size_t)N * 4);
    int*   in_off  = (int*)carve((size_t)(N + 1) * 4);
    int*   out_off = (int*)carve((size_t)(N + 1) * 4);
    int*   cur_in  = (int*)carve((size_t)N * 4);
    int*   cur_out = (int*)carve((size_t)N * 4);
    float* dis     = (float*)carve((size_t)N * 4);
    float* selfw   = (float*)carve((size_t)N * 4);
    int*   csr_in  = (int*)carve((size_t)E * 4);
    int*   csr_out = (int*)carve((size_t)E * 4);
    float* bufA    = (float*)carve((size_t)N * K * 4);   // h2 / v
    float* bufB    = (float*)carve((size_t)N * K * 4);   // u / last
    float* bufC    = (float*)carve((size_t)N * H * 4);   // z
    short* w1t     = (short*)carve((size_t)L * K * DLM * 2);  // [L][128][1024] bf16
    short* w2t     = (short*)carve((size_t)L * K * K * 2);    // [L][128][128] bf16
    (void)ws_size; (void)n_in; (void)out_size;

    // 1) degrees
    hipMemsetAsync(indeg, 0, (size_t)N * 4, stream);
    hipMemsetAsync(outdeg, 0, (size_t)N * 4, stream);
    count_deg_k<<<dim3((E + 255) / 256), 256, 0, stream>>>(ei, E, indeg, outdeg);

    // 2) CSR offsets
    scan_excl2_k<<<dim3(2), 1024, 0, stream>>>(indeg, in_off, outdeg, out_off, N);

    // 3) node constants + cursors
    node_prep_k<<<dim3((N + 255) / 256), 256, 0, stream>>>(N, indeg, in_off, out_off,
                                                           dis, selfw, cur_in, cur_out);

    // 4) CSR fill
    fill_csr_k<<<dim3((E + 255) / 256), 256, 0, stream>>>(ei, E, cur_in, cur_out,
                                                          csr_in, csr_out);

    // 4b) weight transpose + bf16 convert (tiny)
    for (int i = 0; i < L; ++i) {
        transpose_w_k<<<dim3((DLM * K + 255) / 256), 256, 0, stream>>>(
            pW1 + (size_t)i * DLM * K, w1t + (size_t)i * K * DLM, DLM, K);
        transpose_w_k<<<dim3((K * K + 255) / 256), 256, 0, stream>>>(
            pW2 + (size_t)i * K * K, w2t + (size_t)i * K * K, K, K);
    }

    // 5) layers
    for (int i = 0; i < L; ++i) {
        proj_fused_k<<<dim3((N + 63) / 64), 256, 0, stream>>>(
            hidden + (size_t)i * N * DLM,
            w1t + (size_t)i * K * DLM,
            pb1 + (size_t)i * K,
            lng + (size_t)i * K,
            lnb + (size_t)i * K,
            w2t + (size_t)i * K * K,
            pb2 + (size_t)i * K,
            alphas, i,
            (i > 0) ? bufB : nullptr,
            bufA, N);

        // u = A_hat @ h2
        agg_k<<<dim3((N + 3) / 4), 256, 0, stream>>>(bufA, bufB, in_off, csr_in,
                                                     dis, selfw, nullptr, N);
        // z = relu(u @ gcn_W1 + gcn_b1)
        gemm_bias_k<true><<<dim3((N + 63) / 64, H / 64), 256, 0, stream>>>(
            bufB, gW1 + (size_t)i * K * H, gb1 + (size_t)i * H, bufC, N, K, H);
        // v = z @ gcn_W2
        gemm_bias_k<false><<<dim3((N + 63) / 64, K / 64), 256, 0, stream>>>(
            bufC, gW2 + (size_t)i * H * K, nullptr, bufA, N, H, K);
        // last = A_hat @ v + gcn_b2
        agg_k<<<dim3((N + 3) / 4), 256, 0, stream>>>(bufA, bufB, in_off, csr_in,
                                                     dis, selfw, gb2 + (size_t)i * K, N);
    }

    // 6) pooling + classifier
    pool_clf_k<<<dim3(B), 128, 0, stream>>>(bufB, mapping, in_off, csr_in,
                                            out_off, csr_out, indeg, outdeg,
                                            clfW, clfb, (float*)d_out, C);
}

// Round 3
// 2267.178 us; speedup vs baseline: 1.8385x; 1.3061x over previous
//
#include <hip/hip_runtime.h>
#include <hip/hip_bf16.h>
#include <math.h>

using short8 = __attribute__((ext_vector_type(8))) short;
using f32x4  = __attribute__((ext_vector_type(4))) float;

#define PSTRIDE 2048   // per-batch neighbor table stride (avg ~64, max ~tens)

__device__ __forceinline__ short f2bf(float f) {
    unsigned u = __float_as_uint(f);
    u = (u + 0x7FFFu + ((u >> 16) & 1u)) >> 16;
    return (short)u;
}

// ---------------------------------------------------------------------------
// Graph prep: binned CSR build (dst-binned, 32 nodes per bin)
// ---------------------------------------------------------------------------

__global__ void map_scatter_k(const int* __restrict__ mapping, int* __restrict__ map_idx, int B)
{
    int b = blockIdx.x * blockDim.x + threadIdx.x;
    if (b < B) map_idx[mapping[b]] = b;
}

// Histogram of dst>>5 into 4096 bins via LDS.
__launch_bounds__(1024)
__global__ void bin_count_k(const int* __restrict__ dst, int E, int* __restrict__ bin_cnt)
{
    __shared__ int h[4096];
    for (int i = threadIdx.x; i < 4096; i += 1024) h[i] = 0;
    __syncthreads();
    int base = blockIdx.x * 32768;
#pragma unroll
    for (int i = 0; i < 32; ++i) {
        int e = base + i * 1024 + threadIdx.x;
        if (e < E) atomicAdd(&h[dst[e] >> 5], 1);
    }
    __syncthreads();
    for (int i = threadIdx.x; i < 4096; i += 1024) {
        int c = h[i];
        if (c) atomicAdd(&bin_cnt[i], c);
    }
}

// Exclusive scan of 4096 bin counts (single block), also copies to cursors.
__launch_bounds__(1024)
__global__ void scan_bins_k(const int* __restrict__ cnt, int* __restrict__ off,
                            int* __restrict__ cur)
{
    __shared__ int wsum[16];
    int tid = threadIdx.x, lane = tid & 63, wid = tid >> 6;
    int4 v = ((const int4*)cnt)[tid];
    int s0 = v.x, s1 = s0 + v.y, s2 = s1 + v.z, s3 = s2 + v.w;
    int q = s3;
#pragma unroll
    for (int o = 1; o < 64; o <<= 1) { int t = __shfl_up(q, o); if (lane >= o) q += t; }
    if (lane == 63) wsum[wid] = q;
    __syncthreads();
    if (wid == 0) {
        int w = (lane < 16) ? wsum[lane] : 0;
#pragma unroll
        for (int o = 1; o < 16; o <<= 1) { int t = __shfl_up(w, o); if (lane >= o) w += t; }
        if (lane < 16) wsum[lane] = w;
    }
    __syncthreads();
    int base = (wid ? wsum[wid - 1] : 0) + q - s3;   // exclusive prefix of this quad
    int4 o4; o4.x = base; o4.y = base + s0; o4.z = base + s1; o4.w = base + s2;
    ((int4*)off)[tid] = o4;
    ((int4*)cur)[tid] = o4;
    if (tid == 1023) off[4096] = base + s3;
}

// Scatter (src,dst) pairs into dst-bin regions; also append pooling neighbors
// for mapped nodes.
__launch_bounds__(256)
__global__ void bin_scatter_k(const int* __restrict__ ei, int E,
                              const int* __restrict__ map_idx,
                              int* __restrict__ bin_cur, int2* __restrict__ pairs,
                              int* __restrict__ pcnt, int* __restrict__ pnb)
{
    int e = blockIdx.x * blockDim.x + threadIdx.x;
    if (e >= E) return;
    int s = ei[e];
    int d = ei[E + e];
    int p = atomicAdd(&bin_cur[d >> 5], 1);
    pairs[p] = make_int2(s, d);
    int ms = map_idx[s];
    if (ms >= 0) {
        int i = atomicAdd(&pcnt[ms], 1);
        if (i < PSTRIDE) pnb[ms * PSTRIDE + i] = d;
    }
    int md = map_idx[d];
    if (md >= 0) {
        int i = atomicAdd(&pcnt[md], 1);
        if (i < PSTRIDE) pnb[md * PSTRIDE + i] = s;
    }
}

// Per-bin: count 32 nodes' indegrees (LDS), derive in_off/dis/selfw, then
// scatter csr entries within the bin's L2-resident window.
__launch_bounds__(256)
__global__ void bin_csr_k(const int2* __restrict__ pairs, const int* __restrict__ bin_off,
                          int* __restrict__ csr_in, int* __restrict__ in_off,
                          float* __restrict__ dis, float* __restrict__ selfw, int N)
{
    __shared__ int lcnt[32];
    __shared__ int lofs[32];
    __shared__ int lcur[32];
    int b = blockIdx.x;
    int tid = threadIdx.x;
    if (tid < 32) lcnt[tid] = 0;
    __syncthreads();
    int beg = bin_off[b], end = bin_off[b + 1];
    for (int i = beg + tid; i < end; i += 256)
        atomicAdd(&lcnt[pairs[i].y & 31], 1);
    __syncthreads();
    if (tid == 0) {
        int run = beg;
#pragma unroll
        for (int j = 0; j < 32; ++j) { lofs[j] = run; lcur[j] = run; run += lcnt[j]; }
    }
    __syncthreads();
    int n0 = b * 32;
    if (tid < 32 && n0 + tid < N) {
        in_off[n0 + tid] = lofs[tid];
        float dg = (float)lcnt[tid] + 1.0f;
        dis[n0 + tid] = rsqrtf(dg);
        selfw[n0 + tid] = 1.0f / dg;
    }
    if (b == gridDim.x - 1 && tid == 0) in_off[N] = end;
    for (int i = beg + tid; i < end; i += 256) {
        int2 pr = pairs[i];
        int p = atomicAdd(&lcur[pr.y & 31], 1);
        csr_in[p] = pr.x;
    }
}

// Transpose + fp32->bf16: src [R][Cc] fp32 -> dst [Cc][R] bf16
__global__ void transpose_w_k(const float* __restrict__ src, short* __restrict__ dst,
                              int R, int Cc)
{
    int idx = blockIdx.x * blockDim.x + threadIdx.x;
    if (idx >= R * Cc) return;
    int r = idx / Cc;
    int c = idx - r * Cc;
    dst[(size_t)c * R + r] = f2bf(src[idx]);
}

// ---------------------------------------------------------------------------
// Fused projector (MFMA): h = relu(LN(X@W1 + b1))@W2 + b2, optional sigmoid
// mix with `last`. Block = 256 threads (4 waves), tile = 64 rows x 128 cols.
// ---------------------------------------------------------------------------
__launch_bounds__(256)
__global__ void proj_fused_k(const float* __restrict__ X,
                             const short* __restrict__ W1t,
                             const float* __restrict__ b1,
                             const float* __restrict__ lng,
                             const float* __restrict__ lnb,
                             const short* __restrict__ W2t,
                             const float* __restrict__ b2,
                             const float* __restrict__ alphas, int layer,
                             const float* __restrict__ last,
                             float* __restrict__ out, int nrows)
{
    __shared__ short S[26112];

    const int tid  = threadIdx.x;
    const int lane = tid & 63;
    const int wave = tid >> 6;
    const int g    = lane >> 4;     // k-group / row-group
    const int lr   = lane & 15;     // A-row / B-col / D-col
    const int wrow = wave * 16;
    const int row0 = blockIdx.x * 64;

    f32x4 acc[8];
#pragma unroll
    for (int f = 0; f < 8; ++f) acc[f] = (f32x4){0.f, 0.f, 0.f, 0.f};

    // ---------------- GEMM1: X[64,1024] @ W1[1024,128] -------------------
    for (int k0 = 0; k0 < 1024; k0 += 64) {
        {
            int r  = tid >> 2;
            int c0 = (tid & 3) * 16;
            int gr = row0 + r;
            float4 v0 = make_float4(0.f,0.f,0.f,0.f), v1 = v0, v2 = v0, v3 = v0;
            if (gr < nrows) {
                const float* xp = X + (size_t)gr * 1024 + k0 + c0;
                v0 = *(const float4*)&xp[0];
                v1 = *(const float4*)&xp[4];
                v2 = *(const float4*)&xp[8];
                v3 = *(const float4*)&xp[12];
            }
            short8 p0, p1;
            p0[0]=f2bf(v0.x); p0[1]=f2bf(v0.y); p0[2]=f2bf(v0.z); p0[3]=f2bf(v0.w);
            p0[4]=f2bf(v1.x); p0[5]=f2bf(v1.y); p0[6]=f2bf(v1.z); p0[7]=f2bf(v1.w);
            p1[0]=f2bf(v2.x); p1[1]=f2bf(v2.y); p1[2]=f2bf(v2.z); p1[3]=f2bf(v2.w);
            p1[4]=f2bf(v3.x); p1[5]=f2bf(v3.y); p1[6]=f2bf(v3.z); p1[7]=f2bf(v3.w);
            *(short8*)&S[r * 72 + c0]     = p0;
            *(short8*)&S[r * 72 + c0 + 8] = p1;
        }
        {
            int c  = tid >> 1;
            int kb = (tid & 1) * 32;
            const short* wp = W1t + (size_t)c * 1024 + k0 + kb;
            short* dp = &S[4608 + c * 72 + kb];
#pragma unroll
            for (int m = 0; m < 4; ++m)
                *(short8*)&dp[m * 8] = *(const short8*)&wp[m * 8];
        }
        __syncthreads();
#pragma unroll
        for (int kk = 0; kk < 64; kk += 32) {
            short8 a = *(short8*)&S[(wrow + lr) * 72 + kk + g * 8];
#pragma unroll
            for (int f = 0; f < 8; ++f) {
                short8 b = *(short8*)&S[4608 + (f * 16 + lr) * 72 + kk + g * 8];
                acc[f] = __builtin_amdgcn_mfma_f32_16x16x32_bf16(a, b, acc[f], 0, 0, 0);
            }
        }
        __syncthreads();
    }

    // ---------------- bias + LayerNorm + ReLU -> Hs (bf16) ---------------
    {
        float b1v[8], gv[8], bv[8];
#pragma unroll
        for (int f = 0; f < 8; ++f) {
            int col = f * 16 + lr;
            b1v[f] = b1[col]; gv[f] = lng[col]; bv[f] = lnb[col];
        }
#pragma unroll
        for (int j = 0; j < 4; ++j) {
            float hv[8];
            float s = 0.f, q = 0.f;
#pragma unroll
            for (int f = 0; f < 8; ++f) {
                float t = acc[f][j] + b1v[f];
                hv[f] = t;
                s += t; q += t * t;
            }
#pragma unroll
            for (int m = 1; m < 16; m <<= 1) {
                s += __shfl_xor(s, m);
                q += __shfl_xor(q, m);
            }
            float mean = s * (1.0f / 128.0f);
            float var  = q * (1.0f / 128.0f) - mean * mean;
            float inv  = rsqrtf(var + 1e-5f);
            int rloc = wrow + 4 * g + j;
#pragma unroll
            for (int f = 0; f < 8; ++f) {
                float h = fmaxf((hv[f] - mean) * inv * gv[f] + bv[f], 0.f);
                S[17408 + rloc * 136 + f * 16 + lr] = f2bf(h);
            }
        }
    }
    {
        int c  = tid >> 1;
        int kb = (tid & 1) * 64;
        const short* wp = W2t + (size_t)c * 128 + kb;
        short* dp = &S[c * 136 + kb];
#pragma unroll
        for (int m = 0; m < 8; ++m)
            *(short8*)&dp[m * 8] = *(const short8*)&wp[m * 8];
    }
    __syncthreads();

    // ---------------- GEMM2: Hs[64,128] @ W2[128,128] --------------------
    f32x4 acc2[8];
#pragma unroll
    for (int f = 0; f < 8; ++f) acc2[f] = (f32x4){0.f, 0.f, 0.f, 0.f};
#pragma unroll
    for (int kk = 0; kk < 128; kk += 32) {
        short8 a = *(short8*)&S[17408 + (wrow + lr) * 136 + kk + g * 8];
#pragma unroll
        for (int f = 0; f < 8; ++f) {
            short8 b = *(short8*)&S[(f * 16 + lr) * 136 + kk + g * 8];
            acc2[f] = __builtin_amdgcn_mfma_f32_16x16x32_bf16(a, b, acc2[f], 0, 0, 0);
        }
    }

    float b2v[8];
#pragma unroll
    for (int f = 0; f < 8; ++f) b2v[f] = b2[f * 16 + lr];
    float asig = 0.f, omas = 0.f;
    if (last) {
        float al = alphas[layer];
        asig = 1.0f / (1.0f + expf(-al * 10.0f));   // T = 0.1
        omas = 1.0f - asig;
    }
#pragma unroll
    for (int j = 0; j < 4; ++j) {
        int gr = row0 + wrow + 4 * g + j;
        if (gr >= nrows) continue;
#pragma unroll
        for (int f = 0; f < 8; ++f) {
            int col = f * 16 + lr;
            float o = acc2[f][j] + b2v[f];
            if (last) o = asig * o + omas * last[(size_t)gr * 128 + col];
            out[(size_t)gr * 128 + col] = o;
        }
    }
}

// ---------------------------------------------------------------------------
// AGG: y[n] = dis[n] * sum_{s in in(n)} dis[s]*x[s]  +  selfw[n]*x[n]  (+bias)
// ---------------------------------------------------------------------------
__launch_bounds__(256)
__global__ void agg_k(const float* __restrict__ x, float* __restrict__ y,
                      const int* __restrict__ off, const int* __restrict__ csr,
                      const float* __restrict__ dis, const float* __restrict__ selfw,
                      const float* __restrict__ bias, int N)
{
    int node = blockIdx.x * 4 + (threadIdx.x >> 6);
    if (node >= N) return;
    int lane = threadIdx.x & 63;
    int beg = off[node], end = off[node + 1];
    float2 acc = make_float2(0.f, 0.f);
    for (int e = beg; e < end; ++e) {
        int s = csr[e];
        float w = dis[s];
        float2 xv = *(const float2*)&x[(size_t)s * 128 + lane * 2];
        acc.x = fmaf(w, xv.x, acc.x);
        acc.y = fmaf(w, xv.y, acc.y);
    }
    float dn = dis[node], sw = selfw[node];
    float2 xo = *(const float2*)&x[(size_t)node * 128 + lane * 2];
    float2 r;
    r.x = dn * acc.x + sw * xo.x;
    r.y = dn * acc.y + sw * xo.y;
    if (bias) { r.x += bias[lane * 2]; r.y += bias[lane * 2 + 1]; }
    *(float2*)&y[(size_t)node * 128 + lane * 2] = r;
}

// ---------------------------------------------------------------------------
// Generic small GEMM: C[M,OUT] = A[M,Kd] @ B[Kd,OUT] (+bias) (relu optional)
// ---------------------------------------------------------------------------
template <bool RELU>
__launch_bounds__(256)
__global__ void gemm_bias_k(const float* __restrict__ A, const float* __restrict__ Bm,
                            const float* __restrict__ bias, float* __restrict__ Cm,
                            int M, int Kd, int OUT)
{
    __shared__ float As[64][36];
    __shared__ float Bs[32][68];
    const int tid = threadIdx.x;
    const int tx = tid & 15;
    const int ty = tid >> 4;
    const int m0 = blockIdx.x * 64;
    const int n0 = blockIdx.y * 64;

    float acc[4][4];
#pragma unroll
    for (int r = 0; r < 4; ++r) { acc[r][0]=0.f; acc[r][1]=0.f; acc[r][2]=0.f; acc[r][3]=0.f; }

    for (int k0 = 0; k0 < Kd; k0 += 32) {
#pragma unroll
        for (int it = 0; it < 2; ++it) {
            int r = (tid >> 3) + it * 32;
            int c = (tid & 7) * 4;
            float4 v = make_float4(0.f, 0.f, 0.f, 0.f);
            int gr = m0 + r;
            if (gr < M) v = *(const float4*)&A[(size_t)gr * Kd + k0 + c];
            *(float4*)&As[r][c] = v;
        }
#pragma unroll
        for (int it = 0; it < 2; ++it) {
            int r = (tid >> 4) + it * 16;
            int c = (tid & 15) * 4;
            *(float4*)&Bs[r][c] = *(const float4*)&Bm[(size_t)(k0 + r) * OUT + n0 + c];
        }
        __syncthreads();
#pragma unroll
        for (int kk = 0; kk < 32; ++kk) {
            float4 b4 = *(const float4*)&Bs[kk][tx * 4];
#pragma unroll
            for (int r = 0; r < 4; ++r) {
                float a = As[ty + 16 * r][kk];
                acc[r][0] = fmaf(a, b4.x, acc[r][0]);
                acc[r][1] = fmaf(a, b4.y, acc[r][1]);
                acc[r][2] = fmaf(a, b4.z, acc[r][2]);
                acc[r][3] = fmaf(a, b4.w, acc[r][3]);
            }
        }
        __syncthreads();
    }

    float4 bb = make_float4(0.f, 0.f, 0.f, 0.f);
    if (bias) bb = *(const float4*)&bias[n0 + tx * 4];
#pragma unroll
    for (int r = 0; r < 4; ++r) {
        int gr = m0 + ty + 16 * r;
        if (gr >= M) continue;
        float4 o;
        o.x = acc[r][0] + bb.x;
        o.y = acc[r][1] + bb.y;
        o.z = acc[r][2] + bb.z;
        o.w = acc[r][3] + bb.w;
        if (RELU) {
            o.x = fmaxf(o.x, 0.f); o.y = fmaxf(o.y, 0.f);
            o.z = fmaxf(o.z, 0.f); o.w = fmaxf(o.w, 0.f);
        }
        *(float4*)&Cm[(size_t)gr * OUT + n0 + tx * 4] = o;
    }
}

// ---------------------------------------------------------------------------
// Pooling (mapped nodes only, via pnb table) + classifier.
// ---------------------------------------------------------------------------
__launch_bounds__(128)
__global__ void pool_clf_k(const float* __restrict__ last, const int* __restrict__ mapping,
                           const int* __restrict__ map_idx,
                           const int* __restrict__ pcnt, const int* __restrict__ pnb,
                           const float* __restrict__ clfW, const float* __restrict__ clfb,
                           float* __restrict__ out, int C)
{
    int b = blockIdx.x;
    int tid = threadIdx.x;   // 0..127 = feature dim
    int n = mapping[b];
    int rep = map_idx[n];
    int cnt = pcnt[rep];
    int m = cnt < PSTRIDE ? cnt : PSTRIDE;

    float s = 0.f;
    const int* nb = pnb + (size_t)rep * PSTRIDE;
    for (int i = 0; i < m; ++i)
        s += last[(size_t)nb[i] * 128 + tid];

    float lv = last[(size_t)n * 128 + tid];
    float pooled = (lv + s) / (1.0f + (float)cnt);

    __shared__ float feat[256];
    feat[tid] = lv;
    feat[128 + tid] = pooled;
    __syncthreads();

    for (int c = tid; c < C; c += blockDim.x) {
        float o = clfb[c];
        for (int j = 0; j < 256; ++j) o = fmaf(feat[j], clfW[j * C + c], o);
        out[(size_t)b * C + c] = o;
    }
}

// ---------------------------------------------------------------------------
// Host launcher
// ---------------------------------------------------------------------------
extern "C" void kernel_launch(void* const* d_in, const int* in_sizes, int n_in,
                              void* d_out, int out_size, void* d_ws, size_t ws_size,
                              hipStream_t stream)
{
    const float* hidden = (const float*)d_in[0];
    const float* pW1    = (const float*)d_in[1];
    const float* pb1    = (const float*)d_in[2];
    const float* lng    = (const float*)d_in[3];
    const float* lnb    = (const float*)d_in[4];
    const float* pW2    = (const float*)d_in[5];
    const float* pb2    = (const float*)d_in[6];
    const float* alphas = (const float*)d_in[7];
    const float* gW1    = (const float*)d_in[8];
    const float* gb1    = (const float*)d_in[9];
    const float* gW2    = (const float*)d_in[10];
    const float* gb2    = (const float*)d_in[11];
    const float* clfW   = (const float*)d_in[12];
    const float* clfb   = (const float*)d_in[13];
    const int*   ei     = (const int*)d_in[14];
    const int*   mapping= (const int*)d_in[15];

    const int L   = in_sizes[7];                 // 2
    const int K   = in_sizes[2] / L;             // 128
    const int H   = in_sizes[9] / L;             // 256
    const int C   = in_sizes[13];                // 40
    const int DLM = in_sizes[1] / (L * K);       // 1024
    const int N   = in_sizes[0] / (L * DLM);     // 100000
    const int E   = in_sizes[14] / 2;            // 3200000
    const int B   = in_sizes[15];                // 1024
    const int NBINS = (N + 31) / 32;             // 3125 (<= 4096)

    char* ws = (char*)d_ws;
    size_t off = 0;
    auto carve = [&](size_t bytes) -> char* {
        char* p = ws + off;
        off += (bytes + 255) & ~(size_t)255;
        return p;
    };
    int*   map_idx = (int*)carve((size_t)N * 4);
    int*   pcnt    = (int*)carve((size_t)B * 4);
    int*   pnb     = (int*)carve((size_t)B * PSTRIDE * 4);
    int*   bin_cnt = (int*)carve(4096 * 4);
    int*   bin_off = (int*)carve(4097 * 4);
    int*   bin_cur = (int*)carve(4096 * 4);
    int2*  pairs   = (int2*)carve((size_t)E * 8);
    int*   in_off  = (int*)carve((size_t)(N + 1) * 4);
    float* dis     = (float*)carve((size_t)N * 4);
    float* selfw   = (float*)carve((size_t)N * 4);
    int*   csr_in  = (int*)carve((size_t)E * 4);
    float* bufA    = (float*)carve((size_t)N * K * 4);   // h2 / v
    float* bufB    = (float*)carve((size_t)N * K * 4);   // u / last
    float* bufC    = (float*)carve((size_t)N * H * 4);   // z
    short* w1t     = (short*)carve((size_t)L * K * DLM * 2);
    short* w2t     = (short*)carve((size_t)L * K * K * 2);
    (void)ws_size; (void)n_in; (void)out_size;

    // graph prep
    hipMemsetAsync(bin_cnt, 0, 4096 * 4, stream);
    hipMemsetAsync(map_idx, 0xFF, (size_t)N * 4, stream);
    hipMemsetAsync(pcnt, 0, (size_t)B * 4, stream);
    map_scatter_k<<<dim3((B + 255) / 256), 256, 0, stream>>>(mapping, map_idx, B);
    bin_count_k<<<dim3((E + 32767) / 32768), 1024, 0, stream>>>(ei + E, E, bin_cnt);
    scan_bins_k<<<dim3(1), 1024, 0, stream>>>(bin_cnt, bin_off, bin_cur);
    bin_scatter_k<<<dim3((E + 255) / 256), 256, 0, stream>>>(ei, E, map_idx, bin_cur,
                                                             pairs, pcnt, pnb);
    bin_csr_k<<<dim3(NBINS), 256, 0, stream>>>(pairs, bin_off, csr_in, in_off,
                                               dis, selfw, N);

    // weight transpose + bf16 convert (tiny)
    for (int i = 0; i < L; ++i) {
        transpose_w_k<<<dim3((DLM * K + 255) / 256), 256, 0, stream>>>(
            pW1 + (size_t)i * DLM * K, w1t + (size_t)i * K * DLM, DLM, K);
        transpose_w_k<<<dim3((K * K + 255) / 256), 256, 0, stream>>>(
            pW2 + (size_t)i * K * K, w2t + (size_t)i * K * K, K, K);
    }

    // layers
    for (int i = 0; i < L; ++i) {
        proj_fused_k<<<dim3((N + 63) / 64), 256, 0, stream>>>(
            hidden + (size_t)i * N * DLM,
            w1t + (size_t)i * K * DLM,
            pb1 + (size_t)i * K,
            lng + (size_t)i * K,
            lnb + (size_t)i * K,
            w2t + (size_t)i * K * K,
            pb2 + (size_t)i * K,
            alphas, i,
            (i > 0) ? bufB : nullptr,
            bufA, N);

        agg_k<<<dim3((N + 3) / 4), 256, 0, stream>>>(bufA, bufB, in_off, csr_in,
                                                     dis, selfw, nullptr, N);
        gemm_bias_k<true><<<dim3((N + 63) / 64, H / 64), 256, 0, stream>>>(
            bufB, gW1 + (size_t)i * K * H, gb1 + (size_t)i * H, bufC, N, K, H);
        gemm_bias_k<false><<<dim3((N + 63) / 64, K / 64), 256, 0, stream>>>(
            bufC, gW2 + (size_t)i * H * K, nullptr, bufA, N, H, K);
        agg_k<<<dim3((N + 3) / 4), 256, 0, stream>>>(bufA, bufB, in_off, csr_in,
                                                     dis, selfw, gb2 + (size_t)i * K, N);
    }

    // pooling + classifier
    pool_clf_k<<<dim3(B), 128, 0, stream>>>(bufB, mapping, map_idx, pcnt, pnb,
                                            clfW, clfb, (float*)d_out, C);
}

// Round 4
// 1942.630 us; speedup vs baseline: 2.1456x; 1.1671x over previous
//
#include <hip/hip_runtime.h>
#include <hip/hip_bf16.h>
#include <math.h>

using short8 = __attribute__((ext_vector_type(8))) short;
using f32x4  = __attribute__((ext_vector_type(4))) float;

#define PSTRIDE 2048   // per-batch neighbor table stride

__device__ __forceinline__ short f2bf(float f) {
    unsigned u = __float_as_uint(f);
    u = (u + 0x7FFFu + ((u >> 16) & 1u)) >> 16;
    return (short)u;
}
__device__ __forceinline__ float bf2f(unsigned short u) {
    return __uint_as_float(((unsigned)u) << 16);
}

// ---------------------------------------------------------------------------
// Graph prep: binned CSR build (dst-binned, 32 nodes per bin)
// ---------------------------------------------------------------------------

__global__ void map_scatter_k(const int* __restrict__ mapping, int* __restrict__ map_idx, int B)
{
    int b = blockIdx.x * blockDim.x + threadIdx.x;
    if (b < B) map_idx[mapping[b]] = b;
}

__launch_bounds__(1024)
__global__ void bin_count_k(const int* __restrict__ dst, int E, int* __restrict__ bin_cnt)
{
    __shared__ int h[4096];
    for (int i = threadIdx.x; i < 4096; i += 1024) h[i] = 0;
    __syncthreads();
    int base = blockIdx.x * 32768;
#pragma unroll
    for (int i = 0; i < 32; ++i) {
        int e = base + i * 1024 + threadIdx.x;
        if (e < E) atomicAdd(&h[dst[e] >> 5], 1);
    }
    __syncthreads();
    for (int i = threadIdx.x; i < 4096; i += 1024) {
        int c = h[i];
        if (c) atomicAdd(&bin_cnt[i], c);
    }
}

__launch_bounds__(1024)
__global__ void scan_bins_k(const int* __restrict__ cnt, int* __restrict__ off,
                            int* __restrict__ cur)
{
    __shared__ int wsum[16];
    int tid = threadIdx.x, lane = tid & 63, wid = tid >> 6;
    int4 v = ((const int4*)cnt)[tid];
    int s0 = v.x, s1 = s0 + v.y, s2 = s1 + v.z, s3 = s2 + v.w;
    int q = s3;
#pragma unroll
    for (int o = 1; o < 64; o <<= 1) { int t = __shfl_up(q, o); if (lane >= o) q += t; }
    if (lane == 63) wsum[wid] = q;
    __syncthreads();
    if (wid == 0) {
        int w = (lane < 16) ? wsum[lane] : 0;
#pragma unroll
        for (int o = 1; o < 16; o <<= 1) { int t = __shfl_up(w, o); if (lane >= o) w += t; }
        if (lane < 16) wsum[lane] = w;
    }
    __syncthreads();
    int base = (wid ? wsum[wid - 1] : 0) + q - s3;
    int4 o4; o4.x = base; o4.y = base + s0; o4.z = base + s1; o4.w = base + s2;
    ((int4*)off)[tid] = o4;
    ((int4*)cur)[tid] = o4;
    if (tid == 1023) off[4096] = base + s3;
}

__launch_bounds__(256)
__global__ void bin_scatter_k(const int* __restrict__ ei, int E,
                              const int* __restrict__ map_idx,
                              int* __restrict__ bin_cur, int2* __restrict__ pairs,
                              int* __restrict__ pcnt, int* __restrict__ pnb)
{
    int e = blockIdx.x * blockDim.x + threadIdx.x;
    if (e >= E) return;
    int s = ei[e];
    int d = ei[E + e];
    int p = atomicAdd(&bin_cur[d >> 5], 1);
    pairs[p] = make_int2(s, d);
    int ms = map_idx[s];
    if (ms >= 0) {
        int i = atomicAdd(&pcnt[ms], 1);
        if (i < PSTRIDE) pnb[ms * PSTRIDE + i] = d;
    }
    int md = map_idx[d];
    if (md >= 0) {
        int i = atomicAdd(&pcnt[md], 1);
        if (i < PSTRIDE) pnb[md * PSTRIDE + i] = s;
    }
}

__launch_bounds__(256)
__global__ void bin_csr_k(const int2* __restrict__ pairs, const int* __restrict__ bin_off,
                          int* __restrict__ csr_in, int* __restrict__ in_off,
                          float* __restrict__ dis, float* __restrict__ selfw, int N)
{
    __shared__ int lcnt[32];
    __shared__ int lofs[32];
    __shared__ int lcur[32];
    int b = blockIdx.x;
    int tid = threadIdx.x;
    if (tid < 32) lcnt[tid] = 0;
    __syncthreads();
    int beg = bin_off[b], end = bin_off[b + 1];
    for (int i = beg + tid; i < end; i += 256)
        atomicAdd(&lcnt[pairs[i].y & 31], 1);
    __syncthreads();
    if (tid == 0) {
        int run = beg;
#pragma unroll
        for (int j = 0; j < 32; ++j) { lofs[j] = run; lcur[j] = run; run += lcnt[j]; }
    }
    __syncthreads();
    int n0 = b * 32;
    if (tid < 32 && n0 + tid < N) {
        in_off[n0 + tid] = lofs[tid];
        float dg = (float)lcnt[tid] + 1.0f;
        dis[n0 + tid] = rsqrtf(dg);
        selfw[n0 + tid] = 1.0f / dg;
    }
    if (b == gridDim.x - 1 && tid == 0) in_off[N] = end;
    for (int i = beg + tid; i < end; i += 256) {
        int2 pr = pairs[i];
        int p = atomicAdd(&lcur[pr.y & 31], 1);
        csr_in[p] = pr.x;
    }
}

// Transpose + fp32->bf16: src [R][Cc] fp32 -> dst [Cc][R] bf16
__global__ void transpose_w_k(const float* __restrict__ src, short* __restrict__ dst,
                              int R, int Cc)
{
    int idx = blockIdx.x * blockDim.x + threadIdx.x;
    if (idx >= R * Cc) return;
    int r = idx / Cc;
    int c = idx - r * Cc;
    dst[(size_t)c * R + r] = f2bf(src[idx]);
}

// ---------------------------------------------------------------------------
// Fused projector (MFMA): out(bf16) = relu(LN(X@W1 + b1))@W2 + b2, optional
// sigmoid mix with fp32 `last`. Block = 256 threads (4 waves), 64 rows tile.
// ---------------------------------------------------------------------------
__launch_bounds__(256)
__global__ void proj_fused_k(const float* __restrict__ X,
                             const short* __restrict__ W1t,
                             const float* __restrict__ b1,
                             const float* __restrict__ lng,
                             const float* __restrict__ lnb,
                             const short* __restrict__ W2t,
                             const float* __restrict__ b2,
                             const float* __restrict__ alphas, int layer,
                             const float* __restrict__ last,
                             short* __restrict__ out, int nrows)
{
    __shared__ short S[26112];

    const int tid  = threadIdx.x;
    const int lane = tid & 63;
    const int wave = tid >> 6;
    const int g    = lane >> 4;
    const int lr   = lane & 15;
    const int wrow = wave * 16;
    const int row0 = blockIdx.x * 64;

    f32x4 acc[8];
#pragma unroll
    for (int f = 0; f < 8; ++f) acc[f] = (f32x4){0.f, 0.f, 0.f, 0.f};

    // GEMM1: X[64,1024] @ W1[1024,128]
    for (int k0 = 0; k0 < 1024; k0 += 64) {
        {
            int r  = tid >> 2;
            int c0 = (tid & 3) * 16;
            int gr = row0 + r;
            float4 v0 = make_float4(0.f,0.f,0.f,0.f), v1 = v0, v2 = v0, v3 = v0;
            if (gr < nrows) {
                const float* xp = X + (size_t)gr * 1024 + k0 + c0;
                v0 = *(const float4*)&xp[0];
                v1 = *(const float4*)&xp[4];
                v2 = *(const float4*)&xp[8];
                v3 = *(const float4*)&xp[12];
            }
            short8 p0, p1;
            p0[0]=f2bf(v0.x); p0[1]=f2bf(v0.y); p0[2]=f2bf(v0.z); p0[3]=f2bf(v0.w);
            p0[4]=f2bf(v1.x); p0[5]=f2bf(v1.y); p0[6]=f2bf(v1.z); p0[7]=f2bf(v1.w);
            p1[0]=f2bf(v2.x); p1[1]=f2bf(v2.y); p1[2]=f2bf(v2.z); p1[3]=f2bf(v2.w);
            p1[4]=f2bf(v3.x); p1[5]=f2bf(v3.y); p1[6]=f2bf(v3.z); p1[7]=f2bf(v3.w);
            *(short8*)&S[r * 72 + c0]     = p0;
            *(short8*)&S[r * 72 + c0 + 8] = p1;
        }
        {
            int c  = tid >> 1;
            int kb = (tid & 1) * 32;
            const short* wp = W1t + (size_t)c * 1024 + k0 + kb;
            short* dp = &S[4608 + c * 72 + kb];
#pragma unroll
            for (int m = 0; m < 4; ++m)
                *(short8*)&dp[m * 8] = *(const short8*)&wp[m * 8];
        }
        __syncthreads();
#pragma unroll
        for (int kk = 0; kk < 64; kk += 32) {
            short8 a = *(short8*)&S[(wrow + lr) * 72 + kk + g * 8];
#pragma unroll
            for (int f = 0; f < 8; ++f) {
                short8 b = *(short8*)&S[4608 + (f * 16 + lr) * 72 + kk + g * 8];
                acc[f] = __builtin_amdgcn_mfma_f32_16x16x32_bf16(a, b, acc[f], 0, 0, 0);
            }
        }
        __syncthreads();
    }

    // bias + LayerNorm + ReLU -> Hs (bf16)
    {
        float b1v[8], gv[8], bv[8];
#pragma unroll
        for (int f = 0; f < 8; ++f) {
            int col = f * 16 + lr;
            b1v[f] = b1[col]; gv[f] = lng[col]; bv[f] = lnb[col];
        }
#pragma unroll
        for (int j = 0; j < 4; ++j) {
            float hv[8];
            float s = 0.f, q = 0.f;
#pragma unroll
            for (int f = 0; f < 8; ++f) {
                float t = acc[f][j] + b1v[f];
                hv[f] = t;
                s += t; q += t * t;
            }
#pragma unroll
            for (int m = 1; m < 16; m <<= 1) {
                s += __shfl_xor(s, m);
                q += __shfl_xor(q, m);
            }
            float mean = s * (1.0f / 128.0f);
            float var  = q * (1.0f / 128.0f) - mean * mean;
            float inv  = rsqrtf(var + 1e-5f);
            int rloc = wrow + 4 * g + j;
#pragma unroll
            for (int f = 0; f < 8; ++f) {
                float h = fmaxf((hv[f] - mean) * inv * gv[f] + bv[f], 0.f);
                S[17408 + rloc * 136 + f * 16 + lr] = f2bf(h);
            }
        }
    }
    {
        int c  = tid >> 1;
        int kb = (tid & 1) * 64;
        const short* wp = W2t + (size_t)c * 128 + kb;
        short* dp = &S[c * 136 + kb];
#pragma unroll
        for (int m = 0; m < 8; ++m)
            *(short8*)&dp[m * 8] = *(const short8*)&wp[m * 8];
    }
    __syncthreads();

    // GEMM2: Hs[64,128] @ W2[128,128]
    f32x4 acc2[8];
#pragma unroll
    for (int f = 0; f < 8; ++f) acc2[f] = (f32x4){0.f, 0.f, 0.f, 0.f};
#pragma unroll
    for (int kk = 0; kk < 128; kk += 32) {
        short8 a = *(short8*)&S[17408 + (wrow + lr) * 136 + kk + g * 8];
#pragma unroll
        for (int f = 0; f < 8; ++f) {
            short8 b = *(short8*)&S[(f * 16 + lr) * 136 + kk + g * 8];
            acc2[f] = __builtin_amdgcn_mfma_f32_16x16x32_bf16(a, b, acc2[f], 0, 0, 0);
        }
    }

    float b2v[8];
#pragma unroll
    for (int f = 0; f < 8; ++f) b2v[f] = b2[f * 16 + lr];
    float asig = 0.f, omas = 0.f;
    if (last) {
        float al = alphas[layer];
        asig = 1.0f / (1.0f + expf(-al * 10.0f));   // T = 0.1
        omas = 1.0f - asig;
    }
#pragma unroll
    for (int j = 0; j < 4; ++j) {
        int gr = row0 + wrow + 4 * g + j;
        if (gr >= nrows) continue;
#pragma unroll
        for (int f = 0; f < 8; ++f) {
            int col = f * 16 + lr;
            float o = acc2[f][j] + b2v[f];
            if (last) o = asig * o + omas * last[(size_t)gr * 128 + col];
            out[(size_t)gr * 128 + col] = f2bf(o);
        }
    }
}

// ---------------------------------------------------------------------------
// AGG: y[n] = dis[n]*sum_{s in in(n)} dis[s]*x[s] + selfw[n]*x[n] (+bias)
// x: bf16 [N,128]. One wave per node, 2 bf16 (1 dword) per lane.
// OUT_BF16: y bf16 packed; else y fp32 (float2 per lane).
// ---------------------------------------------------------------------------
template <bool OUT_BF16>
__launch_bounds__(256)
__global__ void agg_k(const unsigned* __restrict__ x, void* __restrict__ y,
                      const int* __restrict__ off, const int* __restrict__ csr,
                      const float* __restrict__ dis, const float* __restrict__ selfw,
                      const float* __restrict__ bias, int N)
{
    int node = blockIdx.x * 4 + (threadIdx.x >> 6);
    if (node >= N) return;
    int lane = threadIdx.x & 63;
    int beg = off[node], end = off[node + 1];
    float accx = 0.f, accy = 0.f;
    for (int e = beg; e < end; ++e) {
        int s = csr[e];
        float w = dis[s];
        unsigned v = x[(size_t)s * 64 + lane];
        accx = fmaf(w, __uint_as_float(v << 16), accx);
        accy = fmaf(w, __uint_as_float(v & 0xFFFF0000u), accy);
    }
    float dn = dis[node], sw = selfw[node];
    unsigned vo = x[(size_t)node * 64 + lane];
    float rx = dn * accx + sw * __uint_as_float(vo << 16);
    float ry = dn * accy + sw * __uint_as_float(vo & 0xFFFF0000u);
    if (bias) { rx += bias[lane * 2]; ry += bias[lane * 2 + 1]; }
    if (OUT_BF16) {
        unsigned p = (unsigned)(unsigned short)f2bf(rx) | ((unsigned)(unsigned short)f2bf(ry) << 16);
        ((unsigned*)y)[(size_t)node * 64 + lane] = p;
    } else {
        *(float2*)&((float*)y)[(size_t)node * 128 + lane * 2] = make_float2(rx, ry);
    }
}

// ---------------------------------------------------------------------------
// MFMA GEMM: C[M,NOUT](bf16) = A[M,KD](bf16) @ Bt^T (+bias)(relu)
// Bt: [NOUT][KD] bf16 pre-transposed. 256 threads, 64-row tile, full NOUT.
// ---------------------------------------------------------------------------
template <int KD, int NOUT, bool RELU, bool BIAS>
__launch_bounds__(256)
__global__ void gemm_mfma_k(const short* __restrict__ A, const short* __restrict__ Bt,
                            const float* __restrict__ bias, short* __restrict__ Cm,
                            int M)
{
    constexpr int APAD = KD + 8;
    constexpr int NF = NOUT / 16;
    __shared__ short As[64 * APAD];
    __shared__ short Bs[NOUT * 72];

    const int tid  = threadIdx.x;
    const int lane = tid & 63;
    const int wave = tid >> 6;
    const int g    = lane >> 4;
    const int lr   = lane & 15;
    const int wrow = wave * 16;
    const int m0   = blockIdx.x * 64;

    // stage A fully (64 x KD)
    {
        constexpr int NV = 64 * KD / 8;      // short8 count
#pragma unroll
        for (int it = 0; it < NV / 256; ++it) {
            int i = tid + it * 256;
            int r = i / (KD / 8);
            int c8 = i - r * (KD / 8);
            short8 v = {0,0,0,0,0,0,0,0};
            int gr = m0 + r;
            if (gr < M) v = *(const short8*)&A[(size_t)gr * KD + c8 * 8];
            *(short8*)&As[r * APAD + c8 * 8] = v;
        }
    }

    f32x4 acc[NF];
#pragma unroll
    for (int f = 0; f < NF; ++f) acc[f] = (f32x4){0.f, 0.f, 0.f, 0.f};

    for (int k0 = 0; k0 < KD; k0 += 64) {
        // stage B chunk (NOUT x 64)
#pragma unroll
        for (int it = 0; it < NOUT * 8 / 256; ++it) {
            int i = tid + it * 256;
            int r = i >> 3;
            int c8 = i & 7;
            *(short8*)&Bs[r * 72 + c8 * 8] = *(const short8*)&Bt[(size_t)r * KD + k0 + c8 * 8];
        }
        __syncthreads();
#pragma unroll
        for (int kk = 0; kk < 64; kk += 32) {
            short8 a = *(short8*)&As[(wrow + lr) * APAD + k0 + kk + g * 8];
#pragma unroll
            for (int f = 0; f < NF; ++f) {
                short8 b = *(short8*)&Bs[(f * 16 + lr) * 72 + kk + g * 8];
                acc[f] = __builtin_amdgcn_mfma_f32_16x16x32_bf16(a, b, acc[f], 0, 0, 0);
            }
        }
        __syncthreads();
    }

    float bb[NF];
#pragma unroll
    for (int f = 0; f < NF; ++f) bb[f] = BIAS ? bias[f * 16 + lr] : 0.f;
#pragma unroll
    for (int j = 0; j < 4; ++j) {
        int gr = m0 + wrow + 4 * g + j;
        if (gr >= M) continue;
#pragma unroll
        for (int f = 0; f < NF; ++f) {
            float o = acc[f][j] + bb[f];
            if (RELU) o = fmaxf(o, 0.f);
            Cm[(size_t)gr * NOUT + f * 16 + lr] = f2bf(o);
        }
    }
}

// ---------------------------------------------------------------------------
// Pooling (mapped nodes only, via pnb table) + classifier. last: fp32.
// ---------------------------------------------------------------------------
__launch_bounds__(128)
__global__ void pool_clf_k(const float* __restrict__ last, const int* __restrict__ mapping,
                           const int* __restrict__ map_idx,
                           const int* __restrict__ pcnt, const int* __restrict__ pnb,
                           const float* __restrict__ clfW, const float* __restrict__ clfb,
                           float* __restrict__ out, int C)
{
    int b = blockIdx.x;
    int tid = threadIdx.x;
    int n = mapping[b];
    int rep = map_idx[n];
    int cnt = pcnt[rep];
    int m = cnt < PSTRIDE ? cnt : PSTRIDE;

    float s = 0.f;
    const int* nb = pnb + (size_t)rep * PSTRIDE;
    for (int i = 0; i < m; ++i)
        s += last[(size_t)nb[i] * 128 + tid];

    float lv = last[(size_t)n * 128 + tid];
    float pooled = (lv + s) / (1.0f + (float)cnt);

    __shared__ float feat[256];
    feat[tid] = lv;
    feat[128 + tid] = pooled;
    __syncthreads();

    for (int c = tid; c < C; c += blockDim.x) {
        float o = clfb[c];
        for (int j = 0; j < 256; ++j) o = fmaf(feat[j], clfW[j * C + c], o);
        out[(size_t)b * C + c] = o;
    }
}

// ---------------------------------------------------------------------------
// Host launcher
// ---------------------------------------------------------------------------
extern "C" void kernel_launch(void* const* d_in, const int* in_sizes, int n_in,
                              void* d_out, int out_size, void* d_ws, size_t ws_size,
                              hipStream_t stream)
{
    const float* hidden = (const float*)d_in[0];
    const float* pW1    = (const float*)d_in[1];
    const float* pb1    = (const float*)d_in[2];
    const float* lng    = (const float*)d_in[3];
    const float* lnb    = (const float*)d_in[4];
    const float* pW2    = (const float*)d_in[5];
    const float* pb2    = (const float*)d_in[6];
    const float* alphas = (const float*)d_in[7];
    const float* gW1    = (const float*)d_in[8];
    const float* gb1    = (const float*)d_in[9];
    const float* gW2    = (const float*)d_in[10];
    const float* gb2    = (const float*)d_in[11];
    const float* clfW   = (const float*)d_in[12];
    const float* clfb   = (const float*)d_in[13];
    const int*   ei     = (const int*)d_in[14];
    const int*   mapping= (const int*)d_in[15];

    const int L   = in_sizes[7];                 // 2
    const int K   = in_sizes[2] / L;             // 128
    const int H   = in_sizes[9] / L;             // 256
    const int C   = in_sizes[13];                // 40
    const int DLM = in_sizes[1] / (L * K);       // 1024
    const int N   = in_sizes[0] / (L * DLM);     // 100000
    const int E   = in_sizes[14] / 2;            // 3200000
    const int B   = in_sizes[15];                // 1024
    const int NBINS = (N + 31) / 32;             // 3125 (<= 4096)

    char* ws = (char*)d_ws;
    size_t off = 0;
    auto carve = [&](size_t bytes) -> char* {
        char* p = ws + off;
        off += (bytes + 255) & ~(size_t)255;
        return p;
    };
    int*   map_idx = (int*)carve((size_t)N * 4);
    int*   pcnt    = (int*)carve((size_t)B * 4);
    int*   pnb     = (int*)carve((size_t)B * PSTRIDE * 4);
    int*   bin_cnt = (int*)carve(4096 * 4);
    int*   bin_off = (int*)carve(4097 * 4);
    int*   bin_cur = (int*)carve(4096 * 4);
    int2*  pairs   = (int2*)carve((size_t)E * 8);
    int*   in_off  = (int*)carve((size_t)(N + 1) * 4);
    float* dis     = (float*)carve((size_t)N * 4);
    float* selfw   = (float*)carve((size_t)N * 4);
    int*   csr_in  = (int*)carve((size_t)E * 4);
    short* bufA    = (short*)carve((size_t)N * K * 2);    // h2 / v (bf16)
    short* bufU    = (short*)carve((size_t)N * K * 2);    // u (bf16)
    short* bufZ    = (short*)carve((size_t)N * H * 2);    // z (bf16)
    float* bufLast = (float*)carve((size_t)N * K * 4);    // last (fp32)
    short* w1t     = (short*)carve((size_t)L * K * DLM * 2);
    short* w2t     = (short*)carve((size_t)L * K * K * 2);
    short* gw1t    = (short*)carve((size_t)L * H * K * 2);  // [L][256][128]
    short* gw2t    = (short*)carve((size_t)L * K * H * 2);  // [L][128][256]
    (void)ws_size; (void)n_in; (void)out_size;

    // graph prep
    hipMemsetAsync(bin_cnt, 0, 4096 * 4, stream);
    hipMemsetAsync(map_idx, 0xFF, (size_t)N * 4, stream);
    hipMemsetAsync(pcnt, 0, (size_t)B * 4, stream);
    map_scatter_k<<<dim3((B + 255) / 256), 256, 0, stream>>>(mapping, map_idx, B);
    bin_count_k<<<dim3((E + 32767) / 32768), 1024, 0, stream>>>(ei + E, E, bin_cnt);
    scan_bins_k<<<dim3(1), 1024, 0, stream>>>(bin_cnt, bin_off, bin_cur);
    bin_scatter_k<<<dim3((E + 255) / 256), 256, 0, stream>>>(ei, E, map_idx, bin_cur,
                                                             pairs, pcnt, pnb);
    bin_csr_k<<<dim3(NBINS), 256, 0, stream>>>(pairs, bin_off, csr_in, in_off,
                                               dis, selfw, N);

    // weight transpose + bf16 convert (tiny)
    for (int i = 0; i < L; ++i) {
        transpose_w_k<<<dim3((DLM * K + 255) / 256), 256, 0, stream>>>(
            pW1 + (size_t)i * DLM * K, w1t + (size_t)i * K * DLM, DLM, K);
        transpose_w_k<<<dim3((K * K + 255) / 256), 256, 0, stream>>>(
            pW2 + (size_t)i * K * K, w2t + (size_t)i * K * K, K, K);
        transpose_w_k<<<dim3((K * H + 255) / 256), 256, 0, stream>>>(
            gW1 + (size_t)i * K * H, gw1t + (size_t)i * H * K, K, H);
        transpose_w_k<<<dim3((H * K + 255) / 256), 256, 0, stream>>>(
            gW2 + (size_t)i * H * K, gw2t + (size_t)i * K * H, H, K);
    }

    const int nblk64 = (N + 63) / 64;

    // layers
    for (int i = 0; i < L; ++i) {
        proj_fused_k<<<dim3(nblk64), 256, 0, stream>>>(
            hidden + (size_t)i * N * DLM,
            w1t + (size_t)i * K * DLM,
            pb1 + (size_t)i * K,
            lng + (size_t)i * K,
            lnb + (size_t)i * K,
            w2t + (size_t)i * K * K,
            pb2 + (size_t)i * K,
            alphas, i,
            (i > 0) ? bufLast : nullptr,
            bufA, N);

        // u = A_hat @ h2   (bf16 -> bf16)
        agg_k<true><<<dim3((N + 3) / 4), 256, 0, stream>>>(
            (const unsigned*)bufA, bufU, in_off, csr_in, dis, selfw, nullptr, N);
        // z = relu(u @ gW1 + gb1)
        gemm_mfma_k<128, 256, true, true><<<dim3(nblk64), 256, 0, stream>>>(
            bufU, gw1t + (size_t)i * H * K, gb1 + (size_t)i * H, bufZ, N);
        // v = z @ gW2   (no bias; bias folded into agg2)
        gemm_mfma_k<256, 128, false, false><<<dim3(nblk64), 256, 0, stream>>>(
            bufZ, gw2t + (size_t)i * K * H, nullptr, bufA, N);
        // last = A_hat @ v + gb2   (bf16 -> fp32)
        agg_k<false><<<dim3((N + 3) / 4), 256, 0, stream>>>(
            (const unsigned*)bufA, bufLast, in_off, csr_in, dis, selfw,
            gb2 + (size_t)i * K, N);
    }

    // pooling + classifier
    pool_clf_k<<<dim3(B), 128, 0, stream>>>(bufLast, mapping, map_idx, pcnt, pnb,
                                            clfW, clfb, (float*)d_out, C);
}

// Round 5
// 1284.513 us; speedup vs baseline: 3.2449x; 1.5123x over previous
//
#include <hip/hip_runtime.h>
#include <hip/hip_bf16.h>
#include <math.h>

using short8 = __attribute__((ext_vector_type(8))) short;
using f32x4  = __attribute__((ext_vector_type(4))) float;

#define PSTRIDE 2048   // per-batch neighbor table stride

__device__ __forceinline__ short f2bf(float f) {
    __hip_bfloat16 h = __float2bfloat16(f);   // RNE; compiler fuses pairs to v_cvt_pk_bf16_f32
    return *reinterpret_cast<short*>(&h);
}

// ---------------------------------------------------------------------------
// Graph prep: binned CSR build (dst-binned, 32 nodes per bin)
// ---------------------------------------------------------------------------

__global__ void map_scatter_k(const int* __restrict__ mapping, int* __restrict__ map_idx, int B)
{
    int b = blockIdx.x * blockDim.x + threadIdx.x;
    if (b < B) map_idx[mapping[b]] = b;
}

__launch_bounds__(1024)
__global__ void bin_count_k(const int* __restrict__ dst, int E, int* __restrict__ bin_cnt)
{
    __shared__ int h[4096];
    for (int i = threadIdx.x; i < 4096; i += 1024) h[i] = 0;
    __syncthreads();
    int base = blockIdx.x * 32768;
#pragma unroll
    for (int i = 0; i < 32; ++i) {
        int e = base + i * 1024 + threadIdx.x;
        if (e < E) atomicAdd(&h[dst[e] >> 5], 1);
    }
    __syncthreads();
    for (int i = threadIdx.x; i < 4096; i += 1024) {
        int c = h[i];
        if (c) atomicAdd(&bin_cnt[i], c);
    }
}

__launch_bounds__(1024)
__global__ void scan_bins_k(const int* __restrict__ cnt, int* __restrict__ off,
                            int* __restrict__ cur)
{
    __shared__ int wsum[16];
    int tid = threadIdx.x, lane = tid & 63, wid = tid >> 6;
    int4 v = ((const int4*)cnt)[tid];
    int s0 = v.x, s1 = s0 + v.y, s2 = s1 + v.z, s3 = s2 + v.w;
    int q = s3;
#pragma unroll
    for (int o = 1; o < 64; o <<= 1) { int t = __shfl_up(q, o); if (lane >= o) q += t; }
    if (lane == 63) wsum[wid] = q;
    __syncthreads();
    if (wid == 0) {
        int w = (lane < 16) ? wsum[lane] : 0;
#pragma unroll
        for (int o = 1; o < 16; o <<= 1) { int t = __shfl_up(w, o); if (lane >= o) w += t; }
        if (lane < 16) wsum[lane] = w;
    }
    __syncthreads();
    int base = (wid ? wsum[wid - 1] : 0) + q - s3;
    int4 o4; o4.x = base; o4.y = base + s0; o4.z = base + s1; o4.w = base + s2;
    ((int4*)off)[tid] = o4;
    ((int4*)cur)[tid] = o4;
    if (tid == 1023) off[4096] = base + s3;
}

__launch_bounds__(256)
__global__ void bin_scatter_k(const int* __restrict__ ei, int E,
                              const int* __restrict__ map_idx,
                              int* __restrict__ bin_cur, int2* __restrict__ pairs,
                              int* __restrict__ pcnt, int* __restrict__ pnb)
{
    int e = blockIdx.x * blockDim.x + threadIdx.x;
    if (e >= E) return;
    int s = ei[e];
    int d = ei[E + e];
    int p = atomicAdd(&bin_cur[d >> 5], 1);
    pairs[p] = make_int2(s, d);
    int ms = map_idx[s];
    if (ms >= 0) {
        int i = atomicAdd(&pcnt[ms], 1);
        if (i < PSTRIDE) pnb[ms * PSTRIDE + i] = d;
    }
    int md = map_idx[d];
    if (md >= 0) {
        int i = atomicAdd(&pcnt[md], 1);
        if (i < PSTRIDE) pnb[md * PSTRIDE + i] = s;
    }
}

__launch_bounds__(256)
__global__ void bin_csr_k(const int2* __restrict__ pairs, const int* __restrict__ bin_off,
                          int* __restrict__ csr_in, int* __restrict__ in_off,
                          float* __restrict__ dis, float* __restrict__ selfw, int N)
{
    __shared__ int lcnt[32];
    __shared__ int lofs[32];
    __shared__ int lcur[32];
    int b = blockIdx.x;
    int tid = threadIdx.x;
    if (tid < 32) lcnt[tid] = 0;
    __syncthreads();
    int beg = bin_off[b], end = bin_off[b + 1];
    for (int i = beg + tid; i < end; i += 256)
        atomicAdd(&lcnt[pairs[i].y & 31], 1);
    __syncthreads();
    if (tid == 0) {
        int run = beg;
#pragma unroll
        for (int j = 0; j < 32; ++j) { lofs[j] = run; lcur[j] = run; run += lcnt[j]; }
    }
    __syncthreads();
    int n0 = b * 32;
    if (tid < 32 && n0 + tid < N) {
        in_off[n0 + tid] = lofs[tid];
        float dg = (float)lcnt[tid] + 1.0f;
        dis[n0 + tid] = rsqrtf(dg);
        selfw[n0 + tid] = 1.0f / dg;
    }
    if (b == gridDim.x - 1 && tid == 0) in_off[N] = end;
    for (int i = beg + tid; i < end; i += 256) {
        int2 pr = pairs[i];
        int p = atomicAdd(&lcur[pr.y & 31], 1);
        csr_in[p] = pr.x;
    }
}

// Transpose + fp32->bf16: src [R][Cc] fp32 -> dst [Cc][R] bf16
__global__ void transpose_w_k(const float* __restrict__ src, short* __restrict__ dst,
                              int R, int Cc)
{
    int idx = blockIdx.x * blockDim.x + threadIdx.x;
    if (idx >= R * Cc) return;
    int r = idx / Cc;
    int c = idx - r * Cc;
    dst[(size_t)c * R + r] = f2bf(src[idx]);
}

// ---------------------------------------------------------------------------
// Fused projector (MFMA): out(bf16) = relu(LN(X@W1 + b1))@W2 + b2, optional
// sigmoid mix with fp32 `last`. Block = 256 threads (4 waves), 64 rows tile.
// ---------------------------------------------------------------------------
__launch_bounds__(256)
__global__ void proj_fused_k(const float* __restrict__ X,
                             const short* __restrict__ W1t,
                             const float* __restrict__ b1,
                             const float* __restrict__ lng,
                             const float* __restrict__ lnb,
                             const short* __restrict__ W2t,
                             const float* __restrict__ b2,
                             const float* __restrict__ alphas, int layer,
                             const float* __restrict__ last,
                             short* __restrict__ out, int nrows)
{
    __shared__ short S[26112];

    const int tid  = threadIdx.x;
    const int lane = tid & 63;
    const int wave = tid >> 6;
    const int g    = lane >> 4;
    const int lr   = lane & 15;
    const int wrow = wave * 16;
    const int row0 = blockIdx.x * 64;

    f32x4 acc[8];
#pragma unroll
    for (int f = 0; f < 8; ++f) acc[f] = (f32x4){0.f, 0.f, 0.f, 0.f};

    // GEMM1: X[64,1024] @ W1[1024,128]
    for (int k0 = 0; k0 < 1024; k0 += 64) {
        {
            int r  = tid >> 2;
            int c0 = (tid & 3) * 16;
            int gr = row0 + r;
            float4 v0 = make_float4(0.f,0.f,0.f,0.f), v1 = v0, v2 = v0, v3 = v0;
            if (gr < nrows) {
                const float* xp = X + (size_t)gr * 1024 + k0 + c0;
                v0 = *(const float4*)&xp[0];
                v1 = *(const float4*)&xp[4];
                v2 = *(const float4*)&xp[8];
                v3 = *(const float4*)&xp[12];
            }
            short8 p0, p1;
            p0[0]=f2bf(v0.x); p0[1]=f2bf(v0.y); p0[2]=f2bf(v0.z); p0[3]=f2bf(v0.w);
            p0[4]=f2bf(v1.x); p0[5]=f2bf(v1.y); p0[6]=f2bf(v1.z); p0[7]=f2bf(v1.w);
            p1[0]=f2bf(v2.x); p1[1]=f2bf(v2.y); p1[2]=f2bf(v2.z); p1[3]=f2bf(v2.w);
            p1[4]=f2bf(v3.x); p1[5]=f2bf(v3.y); p1[6]=f2bf(v3.z); p1[7]=f2bf(v3.w);
            *(short8*)&S[r * 72 + c0]     = p0;
            *(short8*)&S[r * 72 + c0 + 8] = p1;
        }
        {
            int c  = tid >> 1;
            int kb = (tid & 1) * 32;
            const short* wp = W1t + (size_t)c * 1024 + k0 + kb;
            short* dp = &S[4608 + c * 72 + kb];
#pragma unroll
            for (int m = 0; m < 4; ++m)
                *(short8*)&dp[m * 8] = *(const short8*)&wp[m * 8];
        }
        __syncthreads();
#pragma unroll
        for (int kk = 0; kk < 64; kk += 32) {
            short8 a = *(short8*)&S[(wrow + lr) * 72 + kk + g * 8];
#pragma unroll
            for (int f = 0; f < 8; ++f) {
                short8 b = *(short8*)&S[4608 + (f * 16 + lr) * 72 + kk + g * 8];
                acc[f] = __builtin_amdgcn_mfma_f32_16x16x32_bf16(a, b, acc[f], 0, 0, 0);
            }
        }
        __syncthreads();
    }

    // bias + LayerNorm + ReLU -> Hs (bf16)
    {
        float b1v[8], gv[8], bv[8];
#pragma unroll
        for (int f = 0; f < 8; ++f) {
            int col = f * 16 + lr;
            b1v[f] = b1[col]; gv[f] = lng[col]; bv[f] = lnb[col];
        }
#pragma unroll
        for (int j = 0; j < 4; ++j) {
            float hv[8];
            float s = 0.f, q = 0.f;
#pragma unroll
            for (int f = 0; f < 8; ++f) {
                float t = acc[f][j] + b1v[f];
                hv[f] = t;
                s += t; q += t * t;
            }
#pragma unroll
            for (int m = 1; m < 16; m <<= 1) {
                s += __shfl_xor(s, m);
                q += __shfl_xor(q, m);
            }
            float mean = s * (1.0f / 128.0f);
            float var  = q * (1.0f / 128.0f) - mean * mean;
            float inv  = rsqrtf(var + 1e-5f);
            int rloc = wrow + 4 * g + j;
#pragma unroll
            for (int f = 0; f < 8; ++f) {
                float h = fmaxf((hv[f] - mean) * inv * gv[f] + bv[f], 0.f);
                S[17408 + rloc * 136 + f * 16 + lr] = f2bf(h);
            }
        }
    }
    {
        int c  = tid >> 1;
        int kb = (tid & 1) * 64;
        const short* wp = W2t + (size_t)c * 128 + kb;
        short* dp = &S[c * 136 + kb];
#pragma unroll
        for (int m = 0; m < 8; ++m)
            *(short8*)&dp[m * 8] = *(const short8*)&wp[m * 8];
    }
    __syncthreads();

    // GEMM2: Hs[64,128] @ W2[128,128]
    f32x4 acc2[8];
#pragma unroll
    for (int f = 0; f < 8; ++f) acc2[f] = (f32x4){0.f, 0.f, 0.f, 0.f};
#pragma unroll
    for (int kk = 0; kk < 128; kk += 32) {
        short8 a = *(short8*)&S[17408 + (wrow + lr) * 136 + kk + g * 8];
#pragma unroll
        for (int f = 0; f < 8; ++f) {
            short8 b = *(short8*)&S[(f * 16 + lr) * 136 + kk + g * 8];
            acc2[f] = __builtin_amdgcn_mfma_f32_16x16x32_bf16(a, b, acc2[f], 0, 0, 0);
        }
    }

    float b2v[8];
#pragma unroll
    for (int f = 0; f < 8; ++f) b2v[f] = b2[f * 16 + lr];
    float asig = 0.f, omas = 0.f;
    if (last) {
        float al = alphas[layer];
        asig = 1.0f / (1.0f + expf(-al * 10.0f));   // T = 0.1
        omas = 1.0f - asig;
    }
#pragma unroll
    for (int j = 0; j < 4; ++j) {
        int gr = row0 + wrow + 4 * g + j;
        if (gr >= nrows) continue;
#pragma unroll
        for (int f = 0; f < 8; ++f) {
            int col = f * 16 + lr;
            float o = acc2[f][j] + b2v[f];
            if (last) o = asig * o + omas * last[(size_t)gr * 128 + col];
            out[(size_t)gr * 128 + col] = f2bf(o);
        }
    }
}

// ---------------------------------------------------------------------------
// Fused GCN MLP (MFMA): V(bf16) = relu(U @ gW1 + gb1) @ gW2
// U:[N,128] bf16, W1t:[256][128] bf16, W2t:[128][256] bf16, V:[N,128] bf16.
// z kept in LDS. Block = 256 threads (4 waves), 64-row tile.
// LDS (shorts): phase A: AsU[64][136]@0 (17408) + Ws1[256][72]@17408 (18432)
//               phase B: Zs[64][264]@0 (16896) + Ws2[128][72]@16896 (9216)
// total 35840 shorts = 71680 B -> 2 blocks/CU
// ---------------------------------------------------------------------------
__launch_bounds__(256)
__global__ void gcn_mlp_k(const short* __restrict__ U,
                          const short* __restrict__ W1t,
                          const float* __restrict__ gb1,
                          const short* __restrict__ W2t,
                          short* __restrict__ V, int M)
{
    __shared__ short S[35840];

    const int tid  = threadIdx.x;
    const int lane = tid & 63;
    const int wave = tid >> 6;
    const int g    = lane >> 4;
    const int lr   = lane & 15;
    const int wrow = wave * 16;
    const int m0   = blockIdx.x * 64;

    // stage U tile (64 x 128)
#pragma unroll
    for (int it = 0; it < 4; ++it) {
        int i = tid + it * 256;        // 1024 short8 slots
        int r = i >> 4;
        int c8 = i & 15;
        short8 v = {0,0,0,0,0,0,0,0};
        int gr = m0 + r;
        if (gr < M) v = *(const short8*)&U[(size_t)gr * 128 + c8 * 8];
        *(short8*)&S[r * 136 + c8 * 8] = v;
    }

    // ---- phase A: z = relu(U @ W1 + b1), 64x128 @ 128x256 ----
    f32x4 acc[16];
#pragma unroll
    for (int f = 0; f < 16; ++f) acc[f] = (f32x4){0.f, 0.f, 0.f, 0.f};

    for (int k0 = 0; k0 < 128; k0 += 64) {
#pragma unroll
        for (int it = 0; it < 8; ++it) {
            int i = tid + it * 256;    // 2048 slots: 256 rows x 8 c8
            int r = i >> 3;
            int c8 = i & 7;
            *(short8*)&S[17408 + r * 72 + c8 * 8] =
                *(const short8*)&W1t[(size_t)r * 128 + k0 + c8 * 8];
        }
        __syncthreads();
#pragma unroll
        for (int kk = 0; kk < 64; kk += 32) {
            short8 a = *(short8*)&S[(wrow + lr) * 136 + k0 + kk + g * 8];
#pragma unroll
            for (int f = 0; f < 16; ++f) {
                short8 b = *(short8*)&S[17408 + (f * 16 + lr) * 72 + kk + g * 8];
                acc[f] = __builtin_amdgcn_mfma_f32_16x16x32_bf16(a, b, acc[f], 0, 0, 0);
            }
        }
        __syncthreads();
    }

    // write z -> Zs (bf16, pad 264)  [overlaps AsU region; safe after sync]
    {
        float bb[16];
#pragma unroll
        for (int f = 0; f < 16; ++f) bb[f] = gb1[f * 16 + lr];
#pragma unroll
        for (int j = 0; j < 4; ++j) {
            int rloc = wrow + 4 * g + j;
#pragma unroll
            for (int f = 0; f < 16; ++f) {
                float zv = fmaxf(acc[f][j] + bb[f], 0.f);
                S[rloc * 264 + f * 16 + lr] = f2bf(zv);
            }
        }
    }

    // ---- phase B: V = Zs @ W2, 64x256 @ 256x128 ----
    f32x4 acc2[8];
#pragma unroll
    for (int f = 0; f < 8; ++f) acc2[f] = (f32x4){0.f, 0.f, 0.f, 0.f};

    for (int k0 = 0; k0 < 256; k0 += 64) {
#pragma unroll
        for (int it = 0; it < 4; ++it) {
            int i = tid + it * 256;    // 1024 slots: 128 rows x 8 c8
            int r = i >> 3;
            int c8 = i & 7;
            *(short8*)&S[16896 + r * 72 + c8 * 8] =
                *(const short8*)&W2t[(size_t)r * 256 + k0 + c8 * 8];
        }
        __syncthreads();
#pragma unroll
        for (int kk = 0; kk < 64; kk += 32) {
            short8 a = *(short8*)&S[(wrow + lr) * 264 + k0 + kk + g * 8];
#pragma unroll
            for (int f = 0; f < 8; ++f) {
                short8 b = *(short8*)&S[16896 + (f * 16 + lr) * 72 + kk + g * 8];
                acc2[f] = __builtin_amdgcn_mfma_f32_16x16x32_bf16(a, b, acc2[f], 0, 0, 0);
            }
        }
        __syncthreads();
    }

#pragma unroll
    for (int j = 0; j < 4; ++j) {
        int gr = m0 + wrow + 4 * g + j;
        if (gr >= M) continue;
#pragma unroll
        for (int f = 0; f < 8; ++f)
            V[(size_t)gr * 128 + f * 16 + lr] = f2bf(acc2[f][j]);
    }
}

// ---------------------------------------------------------------------------
// AGG: y[n] = dis[n]*sum_{s in in(n)} dis[s]*x[s] + selfw[n]*x[n] (+bias)
// x: bf16 [N,128]. One wave per node, 2 bf16 (1 dword) per lane.
// 4-way unrolled: 4 independent gather/fma streams.
// ---------------------------------------------------------------------------
template <bool OUT_BF16>
__launch_bounds__(256)
__global__ void agg_k(const unsigned* __restrict__ x, void* __restrict__ y,
                      const int* __restrict__ off, const int* __restrict__ csr,
                      const float* __restrict__ dis, const float* __restrict__ selfw,
                      const float* __restrict__ bias, int N)
{
    int node = blockIdx.x * 4 + (threadIdx.x >> 6);
    if (node >= N) return;
    int lane = threadIdx.x & 63;
    int beg = off[node], end = off[node + 1];

    float ax0 = 0.f, ay0 = 0.f, ax1 = 0.f, ay1 = 0.f;
    float ax2 = 0.f, ay2 = 0.f, ax3 = 0.f, ay3 = 0.f;
    int e = beg;
    for (; e + 4 <= end; e += 4) {
        int s0 = csr[e], s1 = csr[e + 1], s2 = csr[e + 2], s3 = csr[e + 3];
        unsigned v0 = x[(size_t)s0 * 64 + lane];
        unsigned v1 = x[(size_t)s1 * 64 + lane];
        unsigned v2 = x[(size_t)s2 * 64 + lane];
        unsigned v3 = x[(size_t)s3 * 64 + lane];
        float w0 = dis[s0], w1 = dis[s1], w2 = dis[s2], w3 = dis[s3];
        ax0 = fmaf(w0, __uint_as_float(v0 << 16), ax0);
        ay0 = fmaf(w0, __uint_as_float(v0 & 0xFFFF0000u), ay0);
        ax1 = fmaf(w1, __uint_as_float(v1 << 16), ax1);
        ay1 = fmaf(w1, __uint_as_float(v1 & 0xFFFF0000u), ay1);
        ax2 = fmaf(w2, __uint_as_float(v2 << 16), ax2);
        ay2 = fmaf(w2, __uint_as_float(v2 & 0xFFFF0000u), ay2);
        ax3 = fmaf(w3, __uint_as_float(v3 << 16), ax3);
        ay3 = fmaf(w3, __uint_as_float(v3 & 0xFFFF0000u), ay3);
    }
    for (; e < end; ++e) {
        int s = csr[e];
        float w = dis[s];
        unsigned v = x[(size_t)s * 64 + lane];
        ax0 = fmaf(w, __uint_as_float(v << 16), ax0);
        ay0 = fmaf(w, __uint_as_float(v & 0xFFFF0000u), ay0);
    }
    float accx = (ax0 + ax1) + (ax2 + ax3);
    float accy = (ay0 + ay1) + (ay2 + ay3);

    float dn = dis[node], sw = selfw[node];
    unsigned vo = x[(size_t)node * 64 + lane];
    float rx = dn * accx + sw * __uint_as_float(vo << 16);
    float ry = dn * accy + sw * __uint_as_float(vo & 0xFFFF0000u);
    if (bias) { rx += bias[lane * 2]; ry += bias[lane * 2 + 1]; }
    if (OUT_BF16) {
        unsigned p = (unsigned)(unsigned short)f2bf(rx) | ((unsigned)(unsigned short)f2bf(ry) << 16);
        ((unsigned*)y)[(size_t)node * 64 + lane] = p;
    } else {
        *(float2*)&((float*)y)[(size_t)node * 128 + lane * 2] = make_float2(rx, ry);
    }
}

// ---------------------------------------------------------------------------
// Pooling (mapped nodes only, via pnb table) + classifier. last: fp32.
// ---------------------------------------------------------------------------
__launch_bounds__(128)
__global__ void pool_clf_k(const float* __restrict__ last, const int* __restrict__ mapping,
                           const int* __restrict__ map_idx,
                           const int* __restrict__ pcnt, const int* __restrict__ pnb,
                           const float* __restrict__ clfW, const float* __restrict__ clfb,
                           float* __restrict__ out, int C)
{
    int b = blockIdx.x;
    int tid = threadIdx.x;
    int n = mapping[b];
    int rep = map_idx[n];
    int cnt = pcnt[rep];
    int m = cnt < PSTRIDE ? cnt : PSTRIDE;

    float s = 0.f;
    const int* nb = pnb + (size_t)rep * PSTRIDE;
    for (int i = 0; i < m; ++i)
        s += last[(size_t)nb[i] * 128 + tid];

    float lv = last[(size_t)n * 128 + tid];
    float pooled = (lv + s) / (1.0f + (float)cnt);

    __shared__ float feat[256];
    feat[tid] = lv;
    feat[128 + tid] = pooled;
    __syncthreads();

    for (int c = tid; c < C; c += blockDim.x) {
        float o = clfb[c];
        for (int j = 0; j < 256; ++j) o = fmaf(feat[j], clfW[j * C + c], o);
        out[(size_t)b * C + c] = o;
    }
}

// ---------------------------------------------------------------------------
// Host launcher
// ---------------------------------------------------------------------------
extern "C" void kernel_launch(void* const* d_in, const int* in_sizes, int n_in,
                              void* d_out, int out_size, void* d_ws, size_t ws_size,
                              hipStream_t stream)
{
    const float* hidden = (const float*)d_in[0];
    const float* pW1    = (const float*)d_in[1];
    const float* pb1    = (const float*)d_in[2];
    const float* lng    = (const float*)d_in[3];
    const float* lnb    = (const float*)d_in[4];
    const float* pW2    = (const float*)d_in[5];
    const float* pb2    = (const float*)d_in[6];
    const float* alphas = (const float*)d_in[7];
    const float* gW1    = (const float*)d_in[8];
    const float* gb1    = (const float*)d_in[9];
    const float* gW2    = (const float*)d_in[10];
    const float* gb2    = (const float*)d_in[11];
    const float* clfW   = (const float*)d_in[12];
    const float* clfb   = (const float*)d_in[13];
    const int*   ei     = (const int*)d_in[14];
    const int*   mapping= (const int*)d_in[15];

    const int L   = in_sizes[7];                 // 2
    const int K   = in_sizes[2] / L;             // 128
    const int H   = in_sizes[9] / L;             // 256
    const int C   = in_sizes[13];                // 40
    const int DLM = in_sizes[1] / (L * K);       // 1024
    const int N   = in_sizes[0] / (L * DLM);     // 100000
    const int E   = in_sizes[14] / 2;            // 3200000
    const int B   = in_sizes[15];                // 1024
    const int NBINS = (N + 31) / 32;             // 3125 (<= 4096)

    char* ws = (char*)d_ws;
    size_t off = 0;
    auto carve = [&](size_t bytes) -> char* {
        char* p = ws + off;
        off += (bytes + 255) & ~(size_t)255;
        return p;
    };
    int*   map_idx = (int*)carve((size_t)N * 4);
    int*   pcnt    = (int*)carve((size_t)B * 4);
    int*   pnb     = (int*)carve((size_t)B * PSTRIDE * 4);
    int*   bin_cnt = (int*)carve(4096 * 4);
    int*   bin_off = (int*)carve(4097 * 4);
    int*   bin_cur = (int*)carve(4096 * 4);
    int2*  pairs   = (int2*)carve((size_t)E * 8);
    int*   in_off  = (int*)carve((size_t)(N + 1) * 4);
    float* dis     = (float*)carve((size_t)N * 4);
    float* selfw   = (float*)carve((size_t)N * 4);
    int*   csr_in  = (int*)carve((size_t)E * 4);
    short* bufA    = (short*)carve((size_t)N * K * 2);    // h2 / v (bf16)
    short* bufU    = (short*)carve((size_t)N * K * 2);    // u (bf16)
    float* bufLast = (float*)carve((size_t)N * K * 4);    // last (fp32)
    short* w1t     = (short*)carve((size_t)L * K * DLM * 2);
    short* w2t     = (short*)carve((size_t)L * K * K * 2);
    short* gw1t    = (short*)carve((size_t)L * H * K * 2);  // [L][256][128]
    short* gw2t    = (short*)carve((size_t)L * K * H * 2);  // [L][128][256]
    (void)ws_size; (void)n_in; (void)out_size;

    // graph prep
    hipMemsetAsync(bin_cnt, 0, 4096 * 4, stream);
    hipMemsetAsync(map_idx, 0xFF, (size_t)N * 4, stream);
    hipMemsetAsync(pcnt, 0, (size_t)B * 4, stream);
    map_scatter_k<<<dim3((B + 255) / 256), 256, 0, stream>>>(mapping, map_idx, B);
    bin_count_k<<<dim3((E + 32767) / 32768), 1024, 0, stream>>>(ei + E, E, bin_cnt);
    scan_bins_k<<<dim3(1), 1024, 0, stream>>>(bin_cnt, bin_off, bin_cur);
    bin_scatter_k<<<dim3((E + 255) / 256), 256, 0, stream>>>(ei, E, map_idx, bin_cur,
                                                             pairs, pcnt, pnb);
    bin_csr_k<<<dim3(NBINS), 256, 0, stream>>>(pairs, bin_off, csr_in, in_off,
                                               dis, selfw, N);

    // weight transpose + bf16 convert (tiny)
    for (int i = 0; i < L; ++i) {
        transpose_w_k<<<dim3((DLM * K + 255) / 256), 256, 0, stream>>>(
            pW1 + (size_t)i * DLM * K, w1t + (size_t)i * K * DLM, DLM, K);
        transpose_w_k<<<dim3((K * K + 255) / 256), 256, 0, stream>>>(
            pW2 + (size_t)i * K * K, w2t + (size_t)i * K * K, K, K);
        transpose_w_k<<<dim3((K * H + 255) / 256), 256, 0, stream>>>(
            gW1 + (size_t)i * K * H, gw1t + (size_t)i * H * K, K, H);
        transpose_w_k<<<dim3((H * K + 255) / 256), 256, 0, stream>>>(
            gW2 + (size_t)i * H * K, gw2t + (size_t)i * K * H, H, K);
    }

    const int nblk64 = (N + 63) / 64;

    // layers
    for (int i = 0; i < L; ++i) {
        proj_fused_k<<<dim3(nblk64), 256, 0, stream>>>(
            hidden + (size_t)i * N * DLM,
            w1t + (size_t)i * K * DLM,
            pb1 + (size_t)i * K,
            lng + (size_t)i * K,
            lnb + (size_t)i * K,
            w2t + (size_t)i * K * K,
            pb2 + (size_t)i * K,
            alphas, i,
            (i > 0) ? bufLast : nullptr,
            bufA, N);

        // u = A_hat @ h2   (bf16 -> bf16)
        agg_k<true><<<dim3((N + 3) / 4), 256, 0, stream>>>(
            (const unsigned*)bufA, bufU, in_off, csr_in, dis, selfw, nullptr, N);
        // v = relu(u @ gW1 + gb1) @ gW2   (fused, z in LDS)
        gcn_mlp_k<<<dim3(nblk64), 256, 0, stream>>>(
            bufU, gw1t + (size_t)i * H * K, gb1 + (size_t)i * H,
            gw2t + (size_t)i * K * H, bufA, N);
        // last = A_hat @ v + gb2   (bf16 -> fp32)
        agg_k<false><<<dim3((N + 3) / 4), 256, 0, stream>>>(
            (const unsigned*)bufA, bufLast, in_off, csr_in, dis, selfw,
            gb2 + (size_t)i * K, N);
    }

    // pooling + classifier
    pool_clf_k<<<dim3(B), 128, 0, stream>>>(bufLast, mapping, map_idx, pcnt, pnb,
                                            clfW, clfb, (float*)d_out, C);
}